// Round 7
// baseline (375.636 us; speedup 1.0000x reference)
//
#include <hip/hip_runtime.h>

#define D_MODEL 2048
#define SEQ 2048
#define BATCH 2
#define NH 16
#define NKV 4
#define HD 128
#define KVD (NKV * HD)              // 512
#define QKVN (D_MODEL + 2 * KVD)    // 3072
#define MROWS (BATCH * SEQ)         // 4096

typedef __attribute__((ext_vector_type(8))) short short8;
typedef __attribute__((ext_vector_type(4))) float f32x4;

__device__ __forceinline__ unsigned short f2bf(float f) {
    union { float f; unsigned int u; } v; v.f = f;
    unsigned int r = (v.u + 0x7FFFu + ((v.u >> 16) & 1u)) >> 16;
    return (unsigned short)r;
}

// round-to-nearest for NON-NEGATIVE floats only (2 ops)
__device__ __forceinline__ unsigned short f2bf_pos(float f) {
    union { float f; unsigned int u; } v; v.f = f;
    return (unsigned short)((v.u + 0x8000u) >> 16);
}

__device__ __forceinline__ float bf2f(unsigned short u) {
    union { float f; unsigned int i; } v; v.i = ((unsigned int)u) << 16;
    return v.f;
}

__device__ __forceinline__ void async16(const void* g, void* l) {
    __builtin_amdgcn_global_load_lds((const __attribute__((address_space(1))) void*)g,
                                     (__attribute__((address_space(3))) void*)l, 16, 0, 0);
}

// ---------------- merged f32 -> bf16 cast for x, Wq, Wk, Wv, Wp (one launch) ----------
__global__ __launch_bounds__(256) void cast_all(const float* __restrict__ x,
                                                const float* __restrict__ wq,
                                                const float* __restrict__ wk,
                                                const float* __restrict__ wv,
                                                const float* __restrict__ wp,
                                                unsigned short* __restrict__ xb,
                                                unsigned short* __restrict__ wqkv,
                                                unsigned short* __restrict__ wpb) {
    int i = blockIdx.x * 256 + threadIdx.x;  // float4 index, regions block-aligned
    const float4* s; ushort4* d; int j;
    if (i < 2097152)      { s = (const float4*)x;  d = (ushort4*)xb;             j = i; }
    else if (i < 3145728) { s = (const float4*)wq; d = (ushort4*)wqkv;           j = i - 2097152; }
    else if (i < 3407872) { s = (const float4*)wk; d = (ushort4*)wqkv + 1048576; j = i - 3145728; }
    else if (i < 3670016) { s = (const float4*)wv; d = (ushort4*)wqkv + 1310720; j = i - 3407872; }
    else                  { s = (const float4*)wp; d = (ushort4*)wpb;            j = i - 3670016; }
    float4 v = s[j];
    ushort4 o;
    o.x = f2bf(v.x); o.y = f2bf(v.y); o.z = f2bf(v.z); o.w = f2bf(v.w);
    d[j] = o;
}

// ---------------- GEMM1 fused, 256x256 8-phase (4 phases x BK=64, dbuf) --------------
// qkv = x @ Wqkv^T with rmsnorm/rope/gain (q,k) or transpose (v) epilogue.
// 8 waves (2M x 4N), per-wave 128x64 output via interleaved halves.
// LDS 128 KB: A[2buf][256][64] + B[2buf][256][64], chunk-XOR swizzled (kc ^= row&7).
// Counted vmcnt: pieces issued A0,B0,B1,A1 per step; waits vmcnt(4) at phases 0,1,3.
// XCD-aware bijective swizzle: 192 blocks -> 24 contiguous per XCD (2 A-panels in L2).
__global__ __launch_bounds__(512) void gemm_qkv(const unsigned short* __restrict__ A,
                                                const unsigned short* __restrict__ W,
                                                const float* __restrict__ gain,
                                                unsigned short* __restrict__ qbuf,
                                                unsigned short* __restrict__ kbuf,
                                                unsigned short* __restrict__ vtb) {
    __shared__ unsigned short smem[65536];   // 128 KB staging; reused as 128x264 out half-tile
    unsigned short* tile = smem;
    const int K = D_MODEL;
    const int tid  = threadIdx.x;
    const int lane = tid & 63;
    const int wave = tid >> 6;
    const int qm   = lane & 15;
    const int quad = lane >> 4;
    const int wr   = wave >> 2;      // 0..1  (M)
    const int wc   = wave & 3;       // 0..3  (N)
    // XCD swizzle (192 = 8 XCD x 24, bijective)
    const int lin = blockIdx.x + 12 * blockIdx.y;
    const int l2  = (lin & 7) * 24 + (lin >> 3);
    const int bx  = l2 % 12;
    const int m0  = (l2 / 12) * 256;
    const int n0 = bx * 256;

    f32x4 acc[2][2][4][2];
#pragma unroll
    for (int a = 0; a < 2; a++)
#pragma unroll
        for (int b = 0; b < 2; b++)
#pragma unroll
            for (int c = 0; c < 4; c++)
#pragma unroll
                for (int d = 0; d < 2; d++) acc[a][b][c][d] = (f32x4){0.f, 0.f, 0.f, 0.f};

    // staging: thread t -> row t>>3 (of 64-row issue), global chunk (t&7)^((t>>3)&7)
    const unsigned short* Asrc = A + (size_t)(m0 + (tid >> 3)) * K + (((tid & 7) ^ ((tid >> 3) & 7)) * 8);
    const unsigned short* Bsrc = W + (size_t)(n0 + (tid >> 3)) * K + (((tid & 7) ^ ((tid >> 3) & 7)) * 8);
    const int dstg = tid * 8;                       // linear LDS dest (ushort)
    // ds_read chunk offsets (swizzle inverse): logical chunk ks*4+quad, XOR row&7 (= qm&7)
    const int ck0 = ((quad ^ (qm & 7)) * 8);
    const int ck1 = (((4 + quad) ^ (qm & 7)) * 8);
    const int arow = wr * 64 + qm;
    const int brow = wc * 32 + qm;

    short8 af[4][2], bf0[2][2], bf1[2][2];

#define STG_A(mh, bufv, kt1) \
    async16(Asrc + (size_t)((mh) * 128) * K + (kt1),      &smem[(bufv) * 16384 + (mh) * 8192 + dstg]); \
    async16(Asrc + (size_t)((mh) * 128 + 64) * K + (kt1), &smem[(bufv) * 16384 + (mh) * 8192 + 4096 + dstg]);
#define STG_B(nh, bufv, kt1) \
    async16(Bsrc + (size_t)((nh) * 128) * K + (kt1),      &smem[32768 + (bufv) * 16384 + (nh) * 8192 + dstg]); \
    async16(Bsrc + (size_t)((nh) * 128 + 64) * K + (kt1), &smem[32768 + (bufv) * 16384 + (nh) * 8192 + 4096 + dstg]);

#define RD_A(ab, mh) { \
    _Pragma("unroll") \
    for (int m = 0; m < 4; m++) { \
        af[m][0] = *(const short8*)&smem[(ab) + ((mh) * 128 + arow + m * 16) * 64 + ck0]; \
        af[m][1] = *(const short8*)&smem[(ab) + ((mh) * 128 + arow + m * 16) * 64 + ck1]; \
    } }
#define RD_B(bb, nh, dstf) { \
    _Pragma("unroll") \
    for (int n = 0; n < 2; n++) { \
        dstf[n][0] = *(const short8*)&smem[(bb) + ((nh) * 128 + brow + n * 16) * 64 + ck0]; \
        dstf[n][1] = *(const short8*)&smem[(bb) + ((nh) * 128 + brow + n * 16) * 64 + ck1]; \
    } }
#define MFMA16(mh, nh, bfr) { \
    __builtin_amdgcn_s_setprio(1); \
    _Pragma("unroll") \
    for (int m = 0; m < 4; m++) \
        _Pragma("unroll") \
        for (int n = 0; n < 2; n++) { \
            acc[mh][nh][m][n] = __builtin_amdgcn_mfma_f32_16x16x32_bf16(af[m][0], bfr[n][0], acc[mh][nh][m][n], 0, 0, 0); \
            acc[mh][nh][m][n] = __builtin_amdgcn_mfma_f32_16x16x32_bf16(af[m][1], bfr[n][1], acc[mh][nh][m][n], 0, 0, 0); \
        } \
    __builtin_amdgcn_s_setprio(0); }

#define BARv asm volatile("s_barrier" ::: "memory")
#define WV4  asm volatile("s_waitcnt vmcnt(4)" ::: "memory")
#define WV2  asm volatile("s_waitcnt vmcnt(2)" ::: "memory")
#define WV0  asm volatile("s_waitcnt vmcnt(0)" ::: "memory")

    // One K-step computing buf p, staging tile t+1 into p^1 (pieces A0,B0,B1,A1)
#define STEP(p, kt1) { \
    /* ph0 (mh0,nh0) */ RD_A((p)*16384, 0) RD_B(32768 + (p)*16384, 0, bf0) STG_A(0, (p)^1, kt1) \
    BARv; MFMA16(0, 0, bf0) WV4; BARv; \
    /* ph1 (mh0,nh1) */ RD_B(32768 + (p)*16384, 1, bf1) STG_B(0, (p)^1, kt1) \
    BARv; MFMA16(0, 1, bf1) WV4; BARv; \
    /* ph2 (mh1,nh0) */ RD_A((p)*16384, 1) STG_B(1, (p)^1, kt1) \
    BARv; MFMA16(1, 0, bf0) BARv; \
    /* ph3 (mh1,nh1) */ STG_A(1, (p)^1, kt1) \
    BARv; MFMA16(1, 1, bf1) WV4; BARv; \
}
    // final K-step: no staging; drain 4 -> 2 -> 0
#define STEPE(p) { \
    RD_A((p)*16384, 0) RD_B(32768 + (p)*16384, 0, bf0) BARv; MFMA16(0, 0, bf0) WV2; BARv; \
    RD_B(32768 + (p)*16384, 1, bf1)                    BARv; MFMA16(0, 1, bf1) WV0; BARv; \
    RD_A((p)*16384, 1)                                 BARv; MFMA16(1, 0, bf0) BARv; \
    MFMA16(1, 1, bf1) \
}

    // prologue: tile 0 -> buf0, piece order A0,B0,B1,A1; wait oldest 4 (A0,B0)
    STG_A(0, 0, 0) STG_B(0, 0, 0) STG_B(1, 0, 0) STG_A(1, 0, 0)
    WV4; BARv;

#pragma unroll 1
    for (int t2 = 0; t2 < 15; ++t2) {
        STEP(0, t2 * 128 + 64)
        STEP(1, t2 * 128 + 128)
    }
    STEP(0, 1984)     // t=30 stages tile 31
    STEPE(1)          // t=31
#undef STG_A
#undef STG_B
#undef RD_A
#undef RD_B
#undef MFMA16
#undef STEP
#undef STEPE

    // ---- fused epilogue, two 128-row halves (out half-tile 128 x 264 in reused LDS) --
    const int s_base = m0 & 2047;   // 256-aligned, batch doesn't split a tile
    const int bb = m0 >> 11;
    const float invf = __builtin_amdgcn_exp2f(-(float)lane * 0.20761871f - 2.6514961f);

#pragma unroll
    for (int half = 0; half < 2; ++half) {
        __syncthreads();   // prior reads (K-loop ds_reads or half-0 processing) done
#pragma unroll
        for (int nh = 0; nh < 2; nh++)
#pragma unroll
            for (int m = 0; m < 4; m++)
#pragma unroll
                for (int n = 0; n < 2; n++)
#pragma unroll
                    for (int r = 0; r < 4; r++) {
                        int row = wr * 64 + m * 16 + quad * 4 + r;
                        int col = nh * 128 + wc * 32 + n * 16 + qm;
                        tile[row * 264 + col] = f2bf(acc[half][nh][m][n][r]);
                    }
        __syncthreads();

        if (bx < 10) {
            // q heads (bx<8): h = 2bx+hh; k heads (bx 8,9): hk = (bx-8)*2+hh
            const bool isq = bx < 8;
#pragma unroll
            for (int hh = 0; hh < 2; hh++) {
                const int h = (isq ? 2 * bx : (bx - 8) * 2) + hh;
                const float g = isq ? gain[h] * 0.12751744f : 1.0f;  // (1/sqrt(128))*log2e folded
                unsigned short* dst = isq
                    ? qbuf + ((size_t)(bb * NH + h) * SEQ + s_base + half * 128) * HD
                    : kbuf + ((size_t)(bb * NKV + h) * SEQ + s_base + half * 128) * HD;
                for (int rr = 0; rr < 16; rr++) {
                    int row = wave * 16 + rr;
                    float x1 = bf2f(tile[row * 264 + hh * 128 + lane]);
                    float x2 = bf2f(tile[row * 264 + hh * 128 + 64 + lane]);
                    float ss = x1 * x1 + x2 * x2;
                    ss += __shfl_xor(ss, 1);  ss += __shfl_xor(ss, 2);  ss += __shfl_xor(ss, 4);
                    ss += __shfl_xor(ss, 8);  ss += __shfl_xor(ss, 16); ss += __shfl_xor(ss, 32);
                    float rs = rsqrtf(ss * (1.0f / 128.0f) + 1.1920929e-07f);
                    float rev = (float)(s_base + half * 128 + row) * invf;  // revolutions, >= 0
                    rev -= truncf(rev);
                    float sn = __builtin_amdgcn_sinf(rev);
                    float cs = __builtin_amdgcn_cosf(rev);
                    float a1 = x1 * rs, a2 = x2 * rs;
                    float o1 = (a1 * cs + a2 * sn) * g;
                    float o2 = (a2 * cs - a1 * sn) * g;
                    dst[(size_t)row * HD + lane]      = f2bf(o1);
                    dst[(size_t)row * HD + 64 + lane] = f2bf(o2);
                }
            }
        } else {
            // v heads: write transposed vt[b][hk][d][s]; hk = (bx-10)*2 + hh
            const int sc = (tid & 31) * 4;
            const int d0 = tid >> 5;      // 0..15
#pragma unroll
            for (int hh = 0; hh < 2; hh++) {
                const int hk = (bx - 10) * 2 + hh;
                unsigned short* dstv = vtb + ((size_t)(bb * NKV + hk) * HD) * SEQ + s_base + half * 128;
#pragma unroll
                for (int i = 0; i < 8; i++) {
                    int d = d0 + 16 * i;
                    ushort4 ov;
                    ov.x = tile[(sc + 0) * 264 + hh * 128 + d];
                    ov.y = tile[(sc + 1) * 264 + hh * 128 + d];
                    ov.z = tile[(sc + 2) * 264 + hh * 128 + d];
                    ov.w = tile[(sc + 3) * 264 + hh * 128 + d];
                    *(ushort4*)(dstv + (size_t)d * SEQ + sc) = ov;
                }
            }
        }
    }
}

// ---------------- GEMM2: C[M,N] = A[M,K] * W[N,K]^T  (bf16 in, fp32 out) --------------
// Double-buffered BK=64, counted vmcnt(4) fused with s_barrier, no drain in main loop.
__global__ __launch_bounds__(256) void gemm_bt(const unsigned short* __restrict__ A,
                                               const unsigned short* __restrict__ W,
                                               float* __restrict__ C, int M, int N, int K) {
    __shared__ unsigned short smem[32768];   // 64 KB
    unsigned short* Al = smem;
    unsigned short* Bl = smem + 16384;
    const int tid  = threadIdx.x;
    const int lane = tid & 63;
    const int wave = tid >> 6;
    const int qm   = lane & 15;
    const int quad = lane >> 4;
    const int m0 = blockIdx.y * 128;
    const int n0 = blockIdx.x * 128;
    const int wm = (wave >> 1) * 64;
    const int wn = (wave & 1) * 64;

    f32x4 acc[4][4];
#pragma unroll
    for (int i = 0; i < 4; i++)
#pragma unroll
        for (int j = 0; j < 4; j++) acc[i][j] = (f32x4){0.f, 0.f, 0.f, 0.f};

    const int r1 = tid >> 2;
    const int c1 = (((tid & 3) ^ ((tid >> 3) & 3)) * 8);
    const unsigned short* Ag = A + (size_t)(m0 + r1) * K + c1;
    const unsigned short* Wg = W + (size_t)(n0 + r1) * K + c1;
    const int stg = wave * 512;
    const int swq = ((qm >> 1) & 3) * 8;

#define STG_B2(khv, bufv) \
    async16(Ag + (khv) * 32,                  &Al[(bufv) * 8192 + (khv) * 4096 + stg]); \
    async16(Ag + (khv) * 32 + (size_t)64 * K, &Al[(bufv) * 8192 + (khv) * 4096 + 2048 + stg]); \
    async16(Wg + (khv) * 32,                  &Bl[(bufv) * 8192 + (khv) * 4096 + stg]); \
    async16(Wg + (khv) * 32 + (size_t)64 * K, &Bl[(bufv) * 8192 + (khv) * 4096 + 2048 + stg]);

#define CMP_B2(bufv, khv) { \
    short8 af[4], bfr[4]; \
    _Pragma("unroll") \
    for (int i = 0; i < 4; i++) { \
        af[i]  = *(const short8*)&Al[(bufv) * 8192 + (khv) * 4096 + (wm + i * 16 + qm) * 32 + (quad * 8 ^ swq)]; \
        bfr[i] = *(const short8*)&Bl[(bufv) * 8192 + (khv) * 4096 + (wn + i * 16 + qm) * 32 + (quad * 8 ^ swq)]; \
    } \
    __builtin_amdgcn_s_setprio(1); \
    _Pragma("unroll") \
    for (int mi = 0; mi < 4; mi++) \
        _Pragma("unroll") \
        for (int ni = 0; ni < 4; ni++) \
            acc[mi][ni] = __builtin_amdgcn_mfma_f32_16x16x32_bf16(af[mi], bfr[ni], acc[mi][ni], 0, 0, 0); \
    __builtin_amdgcn_s_setprio(0); \
}

    STG_B2(0, 0)
    STG_B2(1, 0)
    Ag += 64; Wg += 64;
    asm volatile("s_waitcnt vmcnt(4)\n\ts_barrier" ::: "memory");

    int buf = 0;
    for (int t = 0; t < K / 64 - 1; ++t) {
        STG_B2(0, buf ^ 1)
        CMP_B2(buf, 0)
        asm volatile("s_waitcnt vmcnt(4)\n\ts_barrier" ::: "memory");
        STG_B2(1, buf ^ 1)
        CMP_B2(buf, 1)
        asm volatile("s_waitcnt vmcnt(4)\n\ts_barrier" ::: "memory");
        Ag += 64; Wg += 64;
        buf ^= 1;
    }
    CMP_B2(buf, 0)
    asm volatile("s_waitcnt vmcnt(0)\n\ts_barrier" ::: "memory");
    CMP_B2(buf, 1)
#undef STG_B2
#undef CMP_B2

#pragma unroll
    for (int mi = 0; mi < 4; mi++) {
#pragma unroll
        for (int r = 0; r < 4; r++) {
            int row = m0 + wm + mi * 16 + quad * 4 + r;
            float* Crow = C + (size_t)row * N + n0 + wn + qm;
#pragma unroll
            for (int ni = 0; ni < 4; ni++) Crow[ni * 16] = acc[mi][ni][r];
        }
    }
}

// ---------------- flash attention v7: BKV=64, fixed-cap softmax, T14 async-STAGE -----
// Reg-staged K/V (issue-early / write-late): global loads for tile t+1 issued BEFORE
// tile t's compute; ds_writes AFTER the end-of-tile raw barrier. No vmcnt(0) drain in
// the loop; LDS stays 40 KB -> 4 blocks/CU. LDS byte layout identical to v5.
__global__ __launch_bounds__(256, 4) void attn(const unsigned short* __restrict__ qb,
                                               const unsigned short* __restrict__ kb,
                                               const unsigned short* __restrict__ vt,
                                               const float* __restrict__ gain,
                                               unsigned short* __restrict__ y) {
    __shared__ unsigned short Ks[8192];      // 64 kv-rows x 128 d, swizzled (16 KB)
    __shared__ unsigned short Vs[8192];      // 128 d-rows x 64 s, swizzled (16 KB)
    __shared__ unsigned short plds[4][1024]; // wave-private P: 16 x 64, swizzled (8 KB)
    const int tid  = threadIdx.x;
    const int lane = tid & 63;
    const int wave = tid >> 6;
    const int bh   = blockIdx.x & 31;
    const int g4   = blockIdx.x >> 5;
    const int gg = g4 & 7;
    const int gs = g4 >> 3;
    const int qt64 = (gs == 0) ? gg : (gs == 1) ? (31 - gg) : (gs == 2) ? (8 + gg) : (23 - gg);
    const int h = bh & 15;
    const int b = bh >> 4;
    const int qm   = lane & 15;
    const int quad = lane >> 4;
    const int q0    = qt64 * 64;
    const int qrow0 = q0 + wave * 16;
    const float M = 17.0f * fabsf(gain[h]);

    const unsigned short* Qp = qb + (((size_t)(b * NH + h)) * SEQ + qrow0) * HD;
    const unsigned short* Kp = kb + ((size_t)(b * NKV + (h >> 2))) * SEQ * HD;
    const unsigned short* Vp = vt + ((size_t)(b * NKV + (h >> 2))) * HD * SEQ;

    short8 qf[4];
#pragma unroll
    for (int c = 0; c < 4; c++)
        qf[c] = *(const short8*)(Qp + qm * HD + c * 32 + quad * 8);

    f32x4 o[8];
#pragma unroll
    for (int t = 0; t < 8; t++) o[t] = (f32x4){0.f, 0.f, 0.f, 0.f};
    float lr[4] = {0.f, 0.f, 0.f, 0.f};

    // K staging: slice i covers rows 16i..16i+15; thread t -> row 16i+(t>>4),
    // global chunk (t&15)^(t>>4) (swizzle by row&15). LDS ushort = i*2048 + tid*8.
    const unsigned short* KsA = Kp + (size_t)(tid >> 4) * HD + (((tid & 15) ^ (tid >> 4)) & 15) * 8;
    // V staging: slice i covers d-rows 32i..32i+31; thread t -> d 32i+(t>>3),
    // global chunk (t&7)^((t>>3)&7). LDS ushort = i*2048 + tid*8.
    const unsigned short* VsA = Vp + (size_t)(tid >> 3) * SEQ + (((tid & 7) ^ ((tid >> 3) & 7)) * 8);
    const int dst8 = tid * 8;      // per-thread LDS ushort offset within each 2048 slice
    unsigned short* P = &plds[wave][0];

    short8 kreg[4], vreg[4];
#define LD_KV() { \
    _Pragma("unroll") \
    for (int i = 0; i < 4; i++) { \
        kreg[i] = *(const short8*)(KsA + (size_t)(16 * i) * HD); \
        vreg[i] = *(const short8*)(VsA + (size_t)(32 * i) * SEQ); \
    } \
    KsA += (size_t)64 * HD; \
    VsA += 64; }
#define WR_KV() { \
    _Pragma("unroll") \
    for (int i = 0; i < 4; i++) { \
        *(short8*)&Ks[i * 2048 + dst8] = kreg[i]; \
        *(short8*)&Vs[i * 2048 + dst8] = vreg[i]; \
    } }

    // prologue: tile 0 via regs (advances KsA/VsA to tile 1)
    LD_KV()
    WR_KV()
    __syncthreads();

    const int kvend = q0 + 64;
    for (int kv0 = 0; kv0 < kvend; kv0 += 64) {
        const bool more = (kv0 + 64 < kvend);     // block-uniform
        if (more) LD_KV()                         // issue-early: flight = one full tile

        f32x4 s[4];
#pragma unroll
        for (int g = 0; g < 4; g++) s[g] = (f32x4){0.f, 0.f, 0.f, 0.f};
#pragma unroll
        for (int c = 0; c < 4; c++) {
#pragma unroll
            for (int g = 0; g < 4; g++) {
                short8 kf = *(const short8*)&Ks[(g * 16 + qm) * 128 + (((c * 4 + quad) ^ qm) * 8)];
                s[g] = __builtin_amdgcn_mfma_f32_16x16x32_bf16(qf[c], kf, s[g], 0, 0, 0);
            }
        }
        if (kv0 + 63 > qrow0) {   // final (diagonal) tile only
#pragma unroll
            for (int g = 0; g < 4; g++)
#pragma unroll
                for (int r = 0; r < 4; r++) {
                    int qg = qrow0 + quad * 4 + r;
                    if (kv0 + g * 16 + qm > qg) s[g][r] = -3.0e38f;
                }
        }
        float p[4][4];
#pragma unroll
        for (int g = 0; g < 4; g++)
#pragma unroll
            for (int r = 0; r < 4; r++) {
                p[g][r] = __builtin_amdgcn_exp2f(s[g][r] - M);
                lr[r] += p[g][r];
            }
        // P: C-layout -> A-layout, swizzled chunks (no pad, conflict-free read)
#pragma unroll
        for (int g = 0; g < 4; g++)
#pragma unroll
            for (int r = 0; r < 4; r++) {
                int rowp = quad * 4 + r;
                P[rowp * 64 + (((g * 2 + (qm >> 3)) ^ (rowp & 7)) * 8) + (qm & 7)] = f2bf_pos(p[g][r]);
            }
        short8 pa[2];
#pragma unroll
        for (int ka = 0; ka < 2; ka++)
            pa[ka] = *(const short8*)&P[qm * 64 + (((ka * 4 + quad) ^ (qm & 7)) * 8)];
#pragma unroll
        for (int t = 0; t < 8; t++) {
#pragma unroll
            for (int ka = 0; ka < 2; ka++) {
                short8 vf = *(const short8*)&Vs[(t * 16 + qm) * 64 + (((ka * 4 + quad) ^ (qm & 7)) * 8)];
                o[t] = __builtin_amdgcn_mfma_f32_16x16x32_bf16(pa[ka], vf, o[t], 0, 0, 0);
            }
        }
        // all waves' LDS reads for tile t are complete at this barrier (each wave's
        // ds_reads resolved before its MFMAs issued); write-late K/V for t+1 after it.
        asm volatile("s_barrier" ::: "memory");
        if (more) WR_KV()                         // compiler inserts the vmcnt wait here
        asm volatile("s_barrier" ::: "memory");
    }
#undef LD_KV
#undef WR_KV
    float rl[4];
#pragma unroll
    for (int r = 0; r < 4; r++) {
        float l = lr[r];
        l += __shfl_xor(l, 1);
        l += __shfl_xor(l, 2);
        l += __shfl_xor(l, 4);
        l += __shfl_xor(l, 8);
        rl[r] = 1.0f / l;
    }
#pragma unroll
    for (int t = 0; t < 8; t++) {
#pragma unroll
        for (int r = 0; r < 4; r++) {
            size_t row = (size_t)(b * SEQ + qrow0 + quad * 4 + r);
            y[row * D_MODEL + h * HD + t * 16 + qm] = f2bf(o[t][r] * rl[r]);
        }
    }
}

extern "C" void kernel_launch(void* const* d_in, const int* in_sizes, int n_in,
                              void* d_out, int out_size, void* d_ws, size_t ws_size,
                              hipStream_t stream) {
    const float* x  = (const float*)d_in[0];
    const float* Wq = (const float*)d_in[1];
    const float* Wk = (const float*)d_in[2];
    const float* Wv = (const float*)d_in[3];
    const float* Wp = (const float*)d_in[4];
    const float* qg = (const float*)d_in[5];

    char* ws = (char*)d_ws;
    unsigned short* xb   = (unsigned short*)(ws + 0);          // 16 MB (reused as y)
    unsigned short* wqkv = (unsigned short*)(ws + 16777216);   // 12 MB
    unsigned short* wp   = (unsigned short*)(ws + 29360128);   // 8 MB
    unsigned short* qbuf = (unsigned short*)(ws + 37748736);   // 16 MB
    unsigned short* kbuf = (unsigned short*)(ws + 54525952);   // 4 MB
    unsigned short* vtb  = (unsigned short*)(ws + 58720256);   // 4 MB
    unsigned short* y    = xb;                                 // alias: xb dead after GEMM1

    cast_all<<<18432, 256, 0, stream>>>(x, Wq, Wk, Wv, Wp, xb, wqkv, wp);
    gemm_qkv<<<dim3(12, 16), 512, 0, stream>>>(xb, wqkv, qg, qbuf, kbuf, vtb);
    attn<<<1024, 256, 0, stream>>>(qbuf, kbuf, vtb, qg, y);
    gemm_bt<<<dim3(16, 32), 256, 0, stream>>>(y, wp, (float*)d_out, MROWS, D_MODEL, D_MODEL);
}

// Round 8
// 280.329 us; speedup vs baseline: 1.3400x; 1.3400x over previous
//
#include <hip/hip_runtime.h>

#define D_MODEL 2048
#define SEQ 2048
#define BATCH 2
#define NH 16
#define NKV 4
#define HD 128
#define KVD (NKV * HD)              // 512
#define QKVN (D_MODEL + 2 * KVD)    // 3072
#define MROWS (BATCH * SEQ)         // 4096

typedef __attribute__((ext_vector_type(8))) short short8;
typedef __attribute__((ext_vector_type(4))) float f32x4;

__device__ __forceinline__ unsigned short f2bf(float f) {
    union { float f; unsigned int u; } v; v.f = f;
    unsigned int r = (v.u + 0x7FFFu + ((v.u >> 16) & 1u)) >> 16;
    return (unsigned short)r;
}

// round-to-nearest for NON-NEGATIVE floats only (2 ops)
__device__ __forceinline__ unsigned short f2bf_pos(float f) {
    union { float f; unsigned int u; } v; v.f = f;
    return (unsigned short)((v.u + 0x8000u) >> 16);
}

__device__ __forceinline__ float bf2f(unsigned short u) {
    union { float f; unsigned int i; } v; v.i = ((unsigned int)u) << 16;
    return v.f;
}

__device__ __forceinline__ void async16(const void* g, void* l) {
    __builtin_amdgcn_global_load_lds((const __attribute__((address_space(1))) void*)g,
                                     (__attribute__((address_space(3))) void*)l, 16, 0, 0);
}

// ---------------- merged f32 -> bf16 cast for x, Wq, Wk, Wv, Wp (one launch) ----------
__global__ __launch_bounds__(256) void cast_all(const float* __restrict__ x,
                                                const float* __restrict__ wq,
                                                const float* __restrict__ wk,
                                                const float* __restrict__ wv,
                                                const float* __restrict__ wp,
                                                unsigned short* __restrict__ xb,
                                                unsigned short* __restrict__ wqkv,
                                                unsigned short* __restrict__ wpb) {
    int i = blockIdx.x * 256 + threadIdx.x;  // float4 index, regions block-aligned
    const float4* s; ushort4* d; int j;
    if (i < 2097152)      { s = (const float4*)x;  d = (ushort4*)xb;             j = i; }
    else if (i < 3145728) { s = (const float4*)wq; d = (ushort4*)wqkv;           j = i - 2097152; }
    else if (i < 3407872) { s = (const float4*)wk; d = (ushort4*)wqkv + 1048576; j = i - 3145728; }
    else if (i < 3670016) { s = (const float4*)wv; d = (ushort4*)wqkv + 1310720; j = i - 3407872; }
    else                  { s = (const float4*)wp; d = (ushort4*)wpb;            j = i - 3670016; }
    float4 v = s[j];
    ushort4 o;
    o.x = f2bf(v.x); o.y = f2bf(v.y); o.z = f2bf(v.z); o.w = f2bf(v.w);
    d[j] = o;
}

// ---------------- GEMM1 fused, 256x256 8-phase (4 phases x BK=64, dbuf) --------------
// qkv = x @ Wqkv^T with rmsnorm/rope/gain (q,k) or transpose (v) epilogue.
// 8 waves (2M x 4N), per-wave 128x64 output via interleaved halves.
// LDS 128 KB: A[2buf][256][64] + B[2buf][256][64], chunk-XOR swizzled (kc ^= row&7).
// Counted vmcnt: pieces issued A0,B0,B1,A1 per step; waits vmcnt(4) at phases 0,1,3.
// XCD-aware bijective swizzle: 192 blocks -> 24 contiguous per XCD (2 A-panels in L2).
__global__ __launch_bounds__(512) void gemm_qkv(const unsigned short* __restrict__ A,
                                                const unsigned short* __restrict__ W,
                                                const float* __restrict__ gain,
                                                unsigned short* __restrict__ qbuf,
                                                unsigned short* __restrict__ kbuf,
                                                unsigned short* __restrict__ vtb) {
    __shared__ unsigned short smem[65536];   // 128 KB staging; reused as 128x264 out half-tile
    unsigned short* tile = smem;
    const int K = D_MODEL;
    const int tid  = threadIdx.x;
    const int lane = tid & 63;
    const int wave = tid >> 6;
    const int qm   = lane & 15;
    const int quad = lane >> 4;
    const int wr   = wave >> 2;      // 0..1  (M)
    const int wc   = wave & 3;       // 0..3  (N)
    // XCD swizzle (192 = 8 XCD x 24, bijective)
    const int lin = blockIdx.x + 12 * blockIdx.y;
    const int l2  = (lin & 7) * 24 + (lin >> 3);
    const int bx  = l2 % 12;
    const int m0  = (l2 / 12) * 256;
    const int n0 = bx * 256;

    f32x4 acc[2][2][4][2];
#pragma unroll
    for (int a = 0; a < 2; a++)
#pragma unroll
        for (int b = 0; b < 2; b++)
#pragma unroll
            for (int c = 0; c < 4; c++)
#pragma unroll
                for (int d = 0; d < 2; d++) acc[a][b][c][d] = (f32x4){0.f, 0.f, 0.f, 0.f};

    // staging: thread t -> row t>>3 (of 64-row issue), global chunk (t&7)^((t>>3)&7)
    const unsigned short* Asrc = A + (size_t)(m0 + (tid >> 3)) * K + (((tid & 7) ^ ((tid >> 3) & 7)) * 8);
    const unsigned short* Bsrc = W + (size_t)(n0 + (tid >> 3)) * K + (((tid & 7) ^ ((tid >> 3) & 7)) * 8);
    const int dstg = tid * 8;                       // linear LDS dest (ushort)
    // ds_read chunk offsets (swizzle inverse): logical chunk ks*4+quad, XOR row&7 (= qm&7)
    const int ck0 = ((quad ^ (qm & 7)) * 8);
    const int ck1 = (((4 + quad) ^ (qm & 7)) * 8);
    const int arow = wr * 64 + qm;
    const int brow = wc * 32 + qm;

    short8 af[4][2], bf0[2][2], bf1[2][2];

#define STG_A(mh, bufv, kt1) \
    async16(Asrc + (size_t)((mh) * 128) * K + (kt1),      &smem[(bufv) * 16384 + (mh) * 8192 + dstg]); \
    async16(Asrc + (size_t)((mh) * 128 + 64) * K + (kt1), &smem[(bufv) * 16384 + (mh) * 8192 + 4096 + dstg]);
#define STG_B(nh, bufv, kt1) \
    async16(Bsrc + (size_t)((nh) * 128) * K + (kt1),      &smem[32768 + (bufv) * 16384 + (nh) * 8192 + dstg]); \
    async16(Bsrc + (size_t)((nh) * 128 + 64) * K + (kt1), &smem[32768 + (bufv) * 16384 + (nh) * 8192 + 4096 + dstg]);

#define RD_A(ab, mh) { \
    _Pragma("unroll") \
    for (int m = 0; m < 4; m++) { \
        af[m][0] = *(const short8*)&smem[(ab) + ((mh) * 128 + arow + m * 16) * 64 + ck0]; \
        af[m][1] = *(const short8*)&smem[(ab) + ((mh) * 128 + arow + m * 16) * 64 + ck1]; \
    } }
#define RD_B(bb, nh, dstf) { \
    _Pragma("unroll") \
    for (int n = 0; n < 2; n++) { \
        dstf[n][0] = *(const short8*)&smem[(bb) + ((nh) * 128 + brow + n * 16) * 64 + ck0]; \
        dstf[n][1] = *(const short8*)&smem[(bb) + ((nh) * 128 + brow + n * 16) * 64 + ck1]; \
    } }
#define MFMA16(mh, nh, bfr) { \
    __builtin_amdgcn_s_setprio(1); \
    _Pragma("unroll") \
    for (int m = 0; m < 4; m++) \
        _Pragma("unroll") \
        for (int n = 0; n < 2; n++) { \
            acc[mh][nh][m][n] = __builtin_amdgcn_mfma_f32_16x16x32_bf16(af[m][0], bfr[n][0], acc[mh][nh][m][n], 0, 0, 0); \
            acc[mh][nh][m][n] = __builtin_amdgcn_mfma_f32_16x16x32_bf16(af[m][1], bfr[n][1], acc[mh][nh][m][n], 0, 0, 0); \
        } \
    __builtin_amdgcn_s_setprio(0); }

#define BARv asm volatile("s_barrier" ::: "memory")
#define WV4  asm volatile("s_waitcnt vmcnt(4)" ::: "memory")
#define WV2  asm volatile("s_waitcnt vmcnt(2)" ::: "memory")
#define WV0  asm volatile("s_waitcnt vmcnt(0)" ::: "memory")

    // One K-step computing buf p, staging tile t+1 into p^1 (pieces A0,B0,B1,A1)
#define STEP(p, kt1) { \
    /* ph0 (mh0,nh0) */ RD_A((p)*16384, 0) RD_B(32768 + (p)*16384, 0, bf0) STG_A(0, (p)^1, kt1) \
    BARv; MFMA16(0, 0, bf0) WV4; BARv; \
    /* ph1 (mh0,nh1) */ RD_B(32768 + (p)*16384, 1, bf1) STG_B(0, (p)^1, kt1) \
    BARv; MFMA16(0, 1, bf1) WV4; BARv; \
    /* ph2 (mh1,nh0) */ RD_A((p)*16384, 1) STG_B(1, (p)^1, kt1) \
    BARv; MFMA16(1, 0, bf0) BARv; \
    /* ph3 (mh1,nh1) */ STG_A(1, (p)^1, kt1) \
    BARv; MFMA16(1, 1, bf1) WV4; BARv; \
}
    // final K-step: no staging; drain 4 -> 2 -> 0
#define STEPE(p) { \
    RD_A((p)*16384, 0) RD_B(32768 + (p)*16384, 0, bf0) BARv; MFMA16(0, 0, bf0) WV2; BARv; \
    RD_B(32768 + (p)*16384, 1, bf1)                    BARv; MFMA16(0, 1, bf1) WV0; BARv; \
    RD_A((p)*16384, 1)                                 BARv; MFMA16(1, 0, bf0) BARv; \
    MFMA16(1, 1, bf1) \
}

    // prologue: tile 0 -> buf0, piece order A0,B0,B1,A1; wait oldest 4 (A0,B0)
    STG_A(0, 0, 0) STG_B(0, 0, 0) STG_B(1, 0, 0) STG_A(1, 0, 0)
    WV4; BARv;

#pragma unroll 1
    for (int t2 = 0; t2 < 15; ++t2) {
        STEP(0, t2 * 128 + 64)
        STEP(1, t2 * 128 + 128)
    }
    STEP(0, 1984)     // t=30 stages tile 31
    STEPE(1)          // t=31
#undef STG_A
#undef STG_B
#undef RD_A
#undef RD_B
#undef MFMA16
#undef STEP
#undef STEPE

    // ---- fused epilogue, two 128-row halves (out half-tile 128 x 264 in reused LDS) --
    const int s_base = m0 & 2047;   // 256-aligned, batch doesn't split a tile
    const int bb = m0 >> 11;
    const float invf = __builtin_amdgcn_exp2f(-(float)lane * 0.20761871f - 2.6514961f);

#pragma unroll
    for (int half = 0; half < 2; ++half) {
        __syncthreads();   // prior reads (K-loop ds_reads or half-0 processing) done
#pragma unroll
        for (int nh = 0; nh < 2; nh++)
#pragma unroll
            for (int m = 0; m < 4; m++)
#pragma unroll
                for (int n = 0; n < 2; n++)
#pragma unroll
                    for (int r = 0; r < 4; r++) {
                        int row = wr * 64 + m * 16 + quad * 4 + r;
                        int col = nh * 128 + wc * 32 + n * 16 + qm;
                        tile[row * 264 + col] = f2bf(acc[half][nh][m][n][r]);
                    }
        __syncthreads();

        if (bx < 10) {
            // q heads (bx<8): h = 2bx+hh; k heads (bx 8,9): hk = (bx-8)*2+hh
            const bool isq = bx < 8;
#pragma unroll
            for (int hh = 0; hh < 2; hh++) {
                const int h = (isq ? 2 * bx : (bx - 8) * 2) + hh;
                const float g = isq ? gain[h] * 0.12751744f : 1.0f;  // (1/sqrt(128))*log2e folded
                unsigned short* dst = isq
                    ? qbuf + ((size_t)(bb * NH + h) * SEQ + s_base + half * 128) * HD
                    : kbuf + ((size_t)(bb * NKV + h) * SEQ + s_base + half * 128) * HD;
                for (int rr = 0; rr < 16; rr++) {
                    int row = wave * 16 + rr;
                    float x1 = bf2f(tile[row * 264 + hh * 128 + lane]);
                    float x2 = bf2f(tile[row * 264 + hh * 128 + 64 + lane]);
                    float ss = x1 * x1 + x2 * x2;
                    ss += __shfl_xor(ss, 1);  ss += __shfl_xor(ss, 2);  ss += __shfl_xor(ss, 4);
                    ss += __shfl_xor(ss, 8);  ss += __shfl_xor(ss, 16); ss += __shfl_xor(ss, 32);
                    float rs = rsqrtf(ss * (1.0f / 128.0f) + 1.1920929e-07f);
                    float rev = (float)(s_base + half * 128 + row) * invf;  // revolutions, >= 0
                    rev -= truncf(rev);
                    float sn = __builtin_amdgcn_sinf(rev);
                    float cs = __builtin_amdgcn_cosf(rev);
                    float a1 = x1 * rs, a2 = x2 * rs;
                    float o1 = (a1 * cs + a2 * sn) * g;
                    float o2 = (a2 * cs - a1 * sn) * g;
                    dst[(size_t)row * HD + lane]      = f2bf(o1);
                    dst[(size_t)row * HD + 64 + lane] = f2bf(o2);
                }
            }
        } else {
            // v heads: write transposed vt[b][hk][d][s]; hk = (bx-10)*2 + hh
            const int sc = (tid & 31) * 4;
            const int d0 = tid >> 5;      // 0..15
#pragma unroll
            for (int hh = 0; hh < 2; hh++) {
                const int hk = (bx - 10) * 2 + hh;
                unsigned short* dstv = vtb + ((size_t)(bb * NKV + hk) * HD) * SEQ + s_base + half * 128;
#pragma unroll
                for (int i = 0; i < 8; i++) {
                    int d = d0 + 16 * i;
                    ushort4 ov;
                    ov.x = tile[(sc + 0) * 264 + hh * 128 + d];
                    ov.y = tile[(sc + 1) * 264 + hh * 128 + d];
                    ov.z = tile[(sc + 2) * 264 + hh * 128 + d];
                    ov.w = tile[(sc + 3) * 264 + hh * 128 + d];
                    *(ushort4*)(dstv + (size_t)d * SEQ + sc) = ov;
                }
            }
        }
    }
}

// ---------------- GEMM2: C[M,N] = A[M,K] * W[N,K]^T  (bf16 in, fp32 out) --------------
// Double-buffered BK=64, counted vmcnt(4) fused with s_barrier, no drain in main loop.
__global__ __launch_bounds__(256) void gemm_bt(const unsigned short* __restrict__ A,
                                               const unsigned short* __restrict__ W,
                                               float* __restrict__ C, int M, int N, int K) {
    __shared__ unsigned short smem[32768];   // 64 KB
    unsigned short* Al = smem;
    unsigned short* Bl = smem + 16384;
    const int tid  = threadIdx.x;
    const int lane = tid & 63;
    const int wave = tid >> 6;
    const int qm   = lane & 15;
    const int quad = lane >> 4;
    const int m0 = blockIdx.y * 128;
    const int n0 = blockIdx.x * 128;
    const int wm = (wave >> 1) * 64;
    const int wn = (wave & 1) * 64;

    f32x4 acc[4][4];
#pragma unroll
    for (int i = 0; i < 4; i++)
#pragma unroll
        for (int j = 0; j < 4; j++) acc[i][j] = (f32x4){0.f, 0.f, 0.f, 0.f};

    const int r1 = tid >> 2;
    const int c1 = (((tid & 3) ^ ((tid >> 3) & 3)) * 8);
    const unsigned short* Ag = A + (size_t)(m0 + r1) * K + c1;
    const unsigned short* Wg = W + (size_t)(n0 + r1) * K + c1;
    const int stg = wave * 512;
    const int swq = ((qm >> 1) & 3) * 8;

#define STG_B2(khv, bufv) \
    async16(Ag + (khv) * 32,                  &Al[(bufv) * 8192 + (khv) * 4096 + stg]); \
    async16(Ag + (khv) * 32 + (size_t)64 * K, &Al[(bufv) * 8192 + (khv) * 4096 + 2048 + stg]); \
    async16(Wg + (khv) * 32,                  &Bl[(bufv) * 8192 + (khv) * 4096 + stg]); \
    async16(Wg + (khv) * 32 + (size_t)64 * K, &Bl[(bufv) * 8192 + (khv) * 4096 + 2048 + stg]);

#define CMP_B2(bufv, khv) { \
    short8 af[4], bfr[4]; \
    _Pragma("unroll") \
    for (int i = 0; i < 4; i++) { \
        af[i]  = *(const short8*)&Al[(bufv) * 8192 + (khv) * 4096 + (wm + i * 16 + qm) * 32 + (quad * 8 ^ swq)]; \
        bfr[i] = *(const short8*)&Bl[(bufv) * 8192 + (khv) * 4096 + (wn + i * 16 + qm) * 32 + (quad * 8 ^ swq)]; \
    } \
    __builtin_amdgcn_s_setprio(1); \
    _Pragma("unroll") \
    for (int mi = 0; mi < 4; mi++) \
        _Pragma("unroll") \
        for (int ni = 0; ni < 4; ni++) \
            acc[mi][ni] = __builtin_amdgcn_mfma_f32_16x16x32_bf16(af[mi], bfr[ni], acc[mi][ni], 0, 0, 0); \
    __builtin_amdgcn_s_setprio(0); \
}

    STG_B2(0, 0)
    STG_B2(1, 0)
    Ag += 64; Wg += 64;
    asm volatile("s_waitcnt vmcnt(4)\n\ts_barrier" ::: "memory");

    int buf = 0;
    for (int t = 0; t < K / 64 - 1; ++t) {
        STG_B2(0, buf ^ 1)
        CMP_B2(buf, 0)
        asm volatile("s_waitcnt vmcnt(4)\n\ts_barrier" ::: "memory");
        STG_B2(1, buf ^ 1)
        CMP_B2(buf, 1)
        asm volatile("s_waitcnt vmcnt(4)\n\ts_barrier" ::: "memory");
        Ag += 64; Wg += 64;
        buf ^= 1;
    }
    CMP_B2(buf, 0)
    asm volatile("s_waitcnt vmcnt(0)\n\ts_barrier" ::: "memory");
    CMP_B2(buf, 1)
#undef STG_B2
#undef CMP_B2

#pragma unroll
    for (int mi = 0; mi < 4; mi++) {
#pragma unroll
        for (int r = 0; r < 4; r++) {
            int row = m0 + wm + mi * 16 + quad * 4 + r;
            float* Crow = C + (size_t)row * N + n0 + wn + qm;
#pragma unroll
            for (int ni = 0; ni < 4; ni++) Crow[ni * 16] = acc[mi][ni][r];
        }
    }
}

// ---------------- flash attention v5 + T5 setprio: BKV=64, fixed-cap softmax ---------
// LDS exactly 40 KB -> 4 blocks/CU. XOR-swizzled K/V/P chunk layouts, zero pad.
// global_load_lds staging (NOT reg-staging: round-7 showed the allocator spills the
// staging regs to scratch -> 234 MB WRITE_SIZE, 2.5x slower).
__global__ __launch_bounds__(256, 4) void attn(const unsigned short* __restrict__ qb,
                                               const unsigned short* __restrict__ kb,
                                               const unsigned short* __restrict__ vt,
                                               const float* __restrict__ gain,
                                               unsigned short* __restrict__ y) {
    __shared__ unsigned short Ks[8192];      // 64 kv-rows x 128 d, swizzled (16 KB)
    __shared__ unsigned short Vs[8192];      // 128 d-rows x 64 s, swizzled (16 KB)
    __shared__ unsigned short plds[4][1024]; // wave-private P: 16 x 64, swizzled (8 KB)
    const int tid  = threadIdx.x;
    const int lane = tid & 63;
    const int wave = tid >> 6;
    const int bh   = blockIdx.x & 31;
    const int g4   = blockIdx.x >> 5;
    const int gg = g4 & 7;
    const int gs = g4 >> 3;
    const int qt64 = (gs == 0) ? gg : (gs == 1) ? (31 - gg) : (gs == 2) ? (8 + gg) : (23 - gg);
    const int h = bh & 15;
    const int b = bh >> 4;
    const int qm   = lane & 15;
    const int quad = lane >> 4;
    const int q0    = qt64 * 64;
    const int qrow0 = q0 + wave * 16;
    const float M = 17.0f * fabsf(gain[h]);

    const unsigned short* Qp = qb + (((size_t)(b * NH + h)) * SEQ + qrow0) * HD;
    const unsigned short* Kp = kb + ((size_t)(b * NKV + (h >> 2))) * SEQ * HD;
    const unsigned short* Vp = vt + ((size_t)(b * NKV + (h >> 2))) * HD * SEQ;

    short8 qf[4];
#pragma unroll
    for (int c = 0; c < 4; c++)
        qf[c] = *(const short8*)(Qp + qm * HD + c * 32 + quad * 8);

    f32x4 o[8];
#pragma unroll
    for (int t = 0; t < 8; t++) o[t] = (f32x4){0.f, 0.f, 0.f, 0.f};
    float lr[4] = {0.f, 0.f, 0.f, 0.f};

    // K staging: issue i covers rows 16i..16i+15; thread t -> row 16i+(t>>4),
    // global chunk (t&15)^(t>>4) (swizzle by row&15). LDS linear = i*2048 + t*8.
    const unsigned short* KsA = Kp + (size_t)(tid >> 4) * HD + (((tid & 15) ^ (tid >> 4)) & 15) * 8;
    // V staging: issue i covers d-rows 32i..32i+31; thread t -> d 32i+(t>>3),
    // global chunk (t&7)^((t>>3)&7). LDS linear = i*2048 + t*8.
    const unsigned short* VsA = Vp + (size_t)(tid >> 3) * SEQ + (((tid & 7) ^ ((tid >> 3) & 7)) * 8);
    char* KsB = (char*)Ks + wave * 1024;
    char* VsB = (char*)Vs + wave * 1024;
    unsigned short* P = &plds[wave][0];

    const int kvend = q0 + 64;
    for (int kv0 = 0; kv0 < kvend; kv0 += 64) {
#pragma unroll
        for (int i = 0; i < 4; i++) {
            async16(KsA + (size_t)(16 * i) * HD,  KsB + i * 4096);
            async16(VsA + (size_t)(32 * i) * SEQ, VsB + i * 4096);
        }
        KsA += (size_t)64 * HD;
        VsA += 64;
        __syncthreads();

        f32x4 s[4];
#pragma unroll
        for (int g = 0; g < 4; g++) s[g] = (f32x4){0.f, 0.f, 0.f, 0.f};
        __builtin_amdgcn_s_setprio(1);
#pragma unroll
        for (int c = 0; c < 4; c++) {
#pragma unroll
            for (int g = 0; g < 4; g++) {
                short8 kf = *(const short8*)&Ks[(g * 16 + qm) * 128 + (((c * 4 + quad) ^ qm) * 8)];
                s[g] = __builtin_amdgcn_mfma_f32_16x16x32_bf16(qf[c], kf, s[g], 0, 0, 0);
            }
        }
        __builtin_amdgcn_s_setprio(0);
        if (kv0 + 63 > qrow0) {   // final (diagonal) tile only
#pragma unroll
            for (int g = 0; g < 4; g++)
#pragma unroll
                for (int r = 0; r < 4; r++) {
                    int qg = qrow0 + quad * 4 + r;
                    if (kv0 + g * 16 + qm > qg) s[g][r] = -3.0e38f;
                }
        }
        float p[4][4];
#pragma unroll
        for (int g = 0; g < 4; g++)
#pragma unroll
            for (int r = 0; r < 4; r++) {
                p[g][r] = __builtin_amdgcn_exp2f(s[g][r] - M);
                lr[r] += p[g][r];
            }
        // P: C-layout -> A-layout, swizzled chunks (no pad, conflict-free read)
#pragma unroll
        for (int g = 0; g < 4; g++)
#pragma unroll
            for (int r = 0; r < 4; r++) {
                int rowp = quad * 4 + r;
                P[rowp * 64 + (((g * 2 + (qm >> 3)) ^ (rowp & 7)) * 8) + (qm & 7)] = f2bf_pos(p[g][r]);
            }
        short8 pa[2];
#pragma unroll
        for (int ka = 0; ka < 2; ka++)
            pa[ka] = *(const short8*)&P[qm * 64 + (((ka * 4 + quad) ^ (qm & 7)) * 8)];
        __builtin_amdgcn_s_setprio(1);
#pragma unroll
        for (int t = 0; t < 8; t++) {
#pragma unroll
            for (int ka = 0; ka < 2; ka++) {
                short8 vf = *(const short8*)&Vs[(t * 16 + qm) * 64 + (((ka * 4 + quad) ^ (qm & 7)) * 8)];
                o[t] = __builtin_amdgcn_mfma_f32_16x16x32_bf16(pa[ka], vf, o[t], 0, 0, 0);
            }
        }
        __builtin_amdgcn_s_setprio(0);
        __syncthreads();
    }
    float rl[4];
#pragma unroll
    for (int r = 0; r < 4; r++) {
        float l = lr[r];
        l += __shfl_xor(l, 1);
        l += __shfl_xor(l, 2);
        l += __shfl_xor(l, 4);
        l += __shfl_xor(l, 8);
        rl[r] = 1.0f / l;
    }
#pragma unroll
    for (int t = 0; t < 8; t++) {
#pragma unroll
        for (int r = 0; r < 4; r++) {
            size_t row = (size_t)(b * SEQ + qrow0 + quad * 4 + r);
            y[row * D_MODEL + h * HD + t * 16 + qm] = f2bf(o[t][r] * rl[r]);
        }
    }
}

extern "C" void kernel_launch(void* const* d_in, const int* in_sizes, int n_in,
                              void* d_out, int out_size, void* d_ws, size_t ws_size,
                              hipStream_t stream) {
    const float* x  = (const float*)d_in[0];
    const float* Wq = (const float*)d_in[1];
    const float* Wk = (const float*)d_in[2];
    const float* Wv = (const float*)d_in[3];
    const float* Wp = (const float*)d_in[4];
    const float* qg = (const float*)d_in[5];

    char* ws = (char*)d_ws;
    unsigned short* xb   = (unsigned short*)(ws + 0);          // 16 MB (reused as y)
    unsigned short* wqkv = (unsigned short*)(ws + 16777216);   // 12 MB
    unsigned short* wp   = (unsigned short*)(ws + 29360128);   // 8 MB
    unsigned short* qbuf = (unsigned short*)(ws + 37748736);   // 16 MB
    unsigned short* kbuf = (unsigned short*)(ws + 54525952);   // 4 MB
    unsigned short* vtb  = (unsigned short*)(ws + 58720256);   // 4 MB
    unsigned short* y    = xb;                                 // alias: xb dead after GEMM1

    cast_all<<<18432, 256, 0, stream>>>(x, Wq, Wk, Wv, Wp, xb, wqkv, wp);
    gemm_qkv<<<dim3(12, 16), 512, 0, stream>>>(xb, wqkv, qg, qbuf, kbuf, vtb);
    attn<<<1024, 256, 0, stream>>>(qbuf, kbuf, vtb, qg, y);
    gemm_bt<<<dim3(16, 32), 256, 0, stream>>>(y, wp, (float*)d_out, MROWS, D_MODEL, D_MODEL);
}

// Round 9
// 275.059 us; speedup vs baseline: 1.3657x; 1.0192x over previous
//
#include <hip/hip_runtime.h>

#define D_MODEL 2048
#define SEQ 2048
#define BATCH 2
#define NH 16
#define NKV 4
#define HD 128
#define KVD (NKV * HD)              // 512
#define QKVN (D_MODEL + 2 * KVD)    // 3072
#define MROWS (BATCH * SEQ)         // 4096

typedef __attribute__((ext_vector_type(8))) short short8;
typedef __attribute__((ext_vector_type(4))) float f32x4;

__device__ __forceinline__ unsigned short f2bf(float f) {
    union { float f; unsigned int u; } v; v.f = f;
    unsigned int r = (v.u + 0x7FFFu + ((v.u >> 16) & 1u)) >> 16;
    return (unsigned short)r;
}

// round-to-nearest for NON-NEGATIVE floats only (2 ops)
__device__ __forceinline__ unsigned short f2bf_pos(float f) {
    union { float f; unsigned int u; } v; v.f = f;
    return (unsigned short)((v.u + 0x8000u) >> 16);
}

__device__ __forceinline__ float bf2f(unsigned short u) {
    union { float f; unsigned int i; } v; v.i = ((unsigned int)u) << 16;
    return v.f;
}

__device__ __forceinline__ void async16(const void* g, void* l) {
    __builtin_amdgcn_global_load_lds((const __attribute__((address_space(1))) void*)g,
                                     (__attribute__((address_space(3))) void*)l, 16, 0, 0);
}

// ---------------- merged f32 -> bf16 cast for x, Wq, Wk, Wv, Wp (one launch) ----------
__global__ __launch_bounds__(256) void cast_all(const float* __restrict__ x,
                                                const float* __restrict__ wq,
                                                const float* __restrict__ wk,
                                                const float* __restrict__ wv,
                                                const float* __restrict__ wp,
                                                unsigned short* __restrict__ xb,
                                                unsigned short* __restrict__ wqkv,
                                                unsigned short* __restrict__ wpb) {
    int i = blockIdx.x * 256 + threadIdx.x;  // float4 index, regions block-aligned
    const float4* s; ushort4* d; int j;
    if (i < 2097152)      { s = (const float4*)x;  d = (ushort4*)xb;             j = i; }
    else if (i < 3145728) { s = (const float4*)wq; d = (ushort4*)wqkv;           j = i - 2097152; }
    else if (i < 3407872) { s = (const float4*)wk; d = (ushort4*)wqkv + 1048576; j = i - 3145728; }
    else if (i < 3670016) { s = (const float4*)wv; d = (ushort4*)wqkv + 1310720; j = i - 3407872; }
    else                  { s = (const float4*)wp; d = (ushort4*)wpb;            j = i - 3670016; }
    float4 v = s[j];
    ushort4 o;
    o.x = f2bf(v.x); o.y = f2bf(v.y); o.z = f2bf(v.z); o.w = f2bf(v.w);
    d[j] = o;
}

// ---------------- GEMM1 fused, 256x256 8-phase (4 phases x BK=64, dbuf) --------------
// qkv = x @ Wqkv^T with rmsnorm/rope/gain (q,k) or transpose (v) epilogue.
// 8 waves (2M x 4N), per-wave 128x64 output via interleaved halves.
// LDS 128 KB: A[2buf][256][64] + B[2buf][256][64], chunk-XOR swizzled (kc ^= row&7).
// Counted vmcnt: pieces issued A0,B0,B1,A1 per step; waits vmcnt(4) at phases 0,1,3.
// XCD-aware bijective swizzle: 192 blocks -> 24 contiguous per XCD (2 A-panels in L2).
__global__ __launch_bounds__(512) void gemm_qkv(const unsigned short* __restrict__ A,
                                                const unsigned short* __restrict__ W,
                                                const float* __restrict__ gain,
                                                unsigned short* __restrict__ qbuf,
                                                unsigned short* __restrict__ kbuf,
                                                unsigned short* __restrict__ vtb) {
    __shared__ unsigned short smem[65536];   // 128 KB staging; reused as 128x264 out half-tile
    unsigned short* tile = smem;
    const int K = D_MODEL;
    const int tid  = threadIdx.x;
    const int lane = tid & 63;
    const int wave = tid >> 6;
    const int qm   = lane & 15;
    const int quad = lane >> 4;
    const int wr   = wave >> 2;      // 0..1  (M)
    const int wc   = wave & 3;       // 0..3  (N)
    // XCD swizzle (192 = 8 XCD x 24, bijective)
    const int lin = blockIdx.x + 12 * blockIdx.y;
    const int l2  = (lin & 7) * 24 + (lin >> 3);
    const int bx  = l2 % 12;
    const int m0  = (l2 / 12) * 256;
    const int n0 = bx * 256;

    f32x4 acc[2][2][4][2];
#pragma unroll
    for (int a = 0; a < 2; a++)
#pragma unroll
        for (int b = 0; b < 2; b++)
#pragma unroll
            for (int c = 0; c < 4; c++)
#pragma unroll
                for (int d = 0; d < 2; d++) acc[a][b][c][d] = (f32x4){0.f, 0.f, 0.f, 0.f};

    // staging: thread t -> row t>>3 (of 64-row issue), global chunk (t&7)^((t>>3)&7)
    const unsigned short* Asrc = A + (size_t)(m0 + (tid >> 3)) * K + (((tid & 7) ^ ((tid >> 3) & 7)) * 8);
    const unsigned short* Bsrc = W + (size_t)(n0 + (tid >> 3)) * K + (((tid & 7) ^ ((tid >> 3) & 7)) * 8);
    const int dstg = tid * 8;                       // linear LDS dest (ushort)
    // ds_read chunk offsets (swizzle inverse): logical chunk ks*4+quad, XOR row&7 (= qm&7)
    const int ck0 = ((quad ^ (qm & 7)) * 8);
    const int ck1 = (((4 + quad) ^ (qm & 7)) * 8);
    const int arow = wr * 64 + qm;
    const int brow = wc * 32 + qm;

    short8 af[4][2], bf0[2][2], bf1[2][2];

#define STG_A(mh, bufv, kt1) \
    async16(Asrc + (size_t)((mh) * 128) * K + (kt1),      &smem[(bufv) * 16384 + (mh) * 8192 + dstg]); \
    async16(Asrc + (size_t)((mh) * 128 + 64) * K + (kt1), &smem[(bufv) * 16384 + (mh) * 8192 + 4096 + dstg]);
#define STG_B(nh, bufv, kt1) \
    async16(Bsrc + (size_t)((nh) * 128) * K + (kt1),      &smem[32768 + (bufv) * 16384 + (nh) * 8192 + dstg]); \
    async16(Bsrc + (size_t)((nh) * 128 + 64) * K + (kt1), &smem[32768 + (bufv) * 16384 + (nh) * 8192 + 4096 + dstg]);

#define RD_A(ab, mh) { \
    _Pragma("unroll") \
    for (int m = 0; m < 4; m++) { \
        af[m][0] = *(const short8*)&smem[(ab) + ((mh) * 128 + arow + m * 16) * 64 + ck0]; \
        af[m][1] = *(const short8*)&smem[(ab) + ((mh) * 128 + arow + m * 16) * 64 + ck1]; \
    } }
#define RD_B(bb, nh, dstf) { \
    _Pragma("unroll") \
    for (int n = 0; n < 2; n++) { \
        dstf[n][0] = *(const short8*)&smem[(bb) + ((nh) * 128 + brow + n * 16) * 64 + ck0]; \
        dstf[n][1] = *(const short8*)&smem[(bb) + ((nh) * 128 + brow + n * 16) * 64 + ck1]; \
    } }
#define MFMA16(mh, nh, bfr) { \
    __builtin_amdgcn_s_setprio(1); \
    _Pragma("unroll") \
    for (int m = 0; m < 4; m++) \
        _Pragma("unroll") \
        for (int n = 0; n < 2; n++) { \
            acc[mh][nh][m][n] = __builtin_amdgcn_mfma_f32_16x16x32_bf16(af[m][0], bfr[n][0], acc[mh][nh][m][n], 0, 0, 0); \
            acc[mh][nh][m][n] = __builtin_amdgcn_mfma_f32_16x16x32_bf16(af[m][1], bfr[n][1], acc[mh][nh][m][n], 0, 0, 0); \
        } \
    __builtin_amdgcn_s_setprio(0); }

#define BARv asm volatile("s_barrier" ::: "memory")
#define WV4  asm volatile("s_waitcnt vmcnt(4)" ::: "memory")
#define WV2  asm volatile("s_waitcnt vmcnt(2)" ::: "memory")
#define WV0  asm volatile("s_waitcnt vmcnt(0)" ::: "memory")

    // One K-step computing buf p, staging tile t+1 into p^1 (pieces A0,B0,B1,A1)
#define STEP(p, kt1) { \
    /* ph0 (mh0,nh0) */ RD_A((p)*16384, 0) RD_B(32768 + (p)*16384, 0, bf0) STG_A(0, (p)^1, kt1) \
    BARv; MFMA16(0, 0, bf0) WV4; BARv; \
    /* ph1 (mh0,nh1) */ RD_B(32768 + (p)*16384, 1, bf1) STG_B(0, (p)^1, kt1) \
    BARv; MFMA16(0, 1, bf1) WV4; BARv; \
    /* ph2 (mh1,nh0) */ RD_A((p)*16384, 1) STG_B(1, (p)^1, kt1) \
    BARv; MFMA16(1, 0, bf0) BARv; \
    /* ph3 (mh1,nh1) */ STG_A(1, (p)^1, kt1) \
    BARv; MFMA16(1, 1, bf1) WV4; BARv; \
}
    // final K-step: no staging; drain 4 -> 2 -> 0
#define STEPE(p) { \
    RD_A((p)*16384, 0) RD_B(32768 + (p)*16384, 0, bf0) BARv; MFMA16(0, 0, bf0) WV2; BARv; \
    RD_B(32768 + (p)*16384, 1, bf1)                    BARv; MFMA16(0, 1, bf1) WV0; BARv; \
    RD_A((p)*16384, 1)                                 BARv; MFMA16(1, 0, bf0) BARv; \
    MFMA16(1, 1, bf1) \
}

    // prologue: tile 0 -> buf0, piece order A0,B0,B1,A1; wait oldest 4 (A0,B0)
    STG_A(0, 0, 0) STG_B(0, 0, 0) STG_B(1, 0, 0) STG_A(1, 0, 0)
    WV4; BARv;

#pragma unroll 1
    for (int t2 = 0; t2 < 15; ++t2) {
        STEP(0, t2 * 128 + 64)
        STEP(1, t2 * 128 + 128)
    }
    STEP(0, 1984)     // t=30 stages tile 31
    STEPE(1)          // t=31
#undef STG_A
#undef STG_B
#undef RD_A
#undef RD_B
#undef MFMA16
#undef STEP
#undef STEPE

    // ---- fused epilogue, two 128-row halves (out half-tile 128 x 264 in reused LDS) --
    const int s_base = m0 & 2047;   // 256-aligned, batch doesn't split a tile
    const int bb = m0 >> 11;
    const float invf = __builtin_amdgcn_exp2f(-(float)lane * 0.20761871f - 2.6514961f);

#pragma unroll
    for (int half = 0; half < 2; ++half) {
        __syncthreads();   // prior reads (K-loop ds_reads or half-0 processing) done
#pragma unroll
        for (int nh = 0; nh < 2; nh++)
#pragma unroll
            for (int m = 0; m < 4; m++)
#pragma unroll
                for (int n = 0; n < 2; n++)
#pragma unroll
                    for (int r = 0; r < 4; r++) {
                        int row = wr * 64 + m * 16 + quad * 4 + r;
                        int col = nh * 128 + wc * 32 + n * 16 + qm;
                        tile[row * 264 + col] = f2bf(acc[half][nh][m][n][r]);
                    }
        __syncthreads();

        if (bx < 10) {
            // q heads (bx<8): h = 2bx+hh; k heads (bx 8,9): hk = (bx-8)*2+hh
            const bool isq = bx < 8;
#pragma unroll
            for (int hh = 0; hh < 2; hh++) {
                const int h = (isq ? 2 * bx : (bx - 8) * 2) + hh;
                const float g = isq ? gain[h] * 0.12751744f : 1.0f;  // (1/sqrt(128))*log2e folded
                unsigned short* dst = isq
                    ? qbuf + ((size_t)(bb * NH + h) * SEQ + s_base + half * 128) * HD
                    : kbuf + ((size_t)(bb * NKV + h) * SEQ + s_base + half * 128) * HD;
                for (int rr = 0; rr < 16; rr++) {
                    int row = wave * 16 + rr;
                    float x1 = bf2f(tile[row * 264 + hh * 128 + lane]);
                    float x2 = bf2f(tile[row * 264 + hh * 128 + 64 + lane]);
                    float ss = x1 * x1 + x2 * x2;
                    ss += __shfl_xor(ss, 1);  ss += __shfl_xor(ss, 2);  ss += __shfl_xor(ss, 4);
                    ss += __shfl_xor(ss, 8);  ss += __shfl_xor(ss, 16); ss += __shfl_xor(ss, 32);
                    float rs = rsqrtf(ss * (1.0f / 128.0f) + 1.1920929e-07f);
                    float rev = (float)(s_base + half * 128 + row) * invf;  // revolutions, >= 0
                    rev -= truncf(rev);
                    float sn = __builtin_amdgcn_sinf(rev);
                    float cs = __builtin_amdgcn_cosf(rev);
                    float a1 = x1 * rs, a2 = x2 * rs;
                    float o1 = (a1 * cs + a2 * sn) * g;
                    float o2 = (a2 * cs - a1 * sn) * g;
                    dst[(size_t)row * HD + lane]      = f2bf(o1);
                    dst[(size_t)row * HD + 64 + lane] = f2bf(o2);
                }
            }
        } else {
            // v heads: write transposed vt[b][hk][d][s]; hk = (bx-10)*2 + hh
            const int sc = (tid & 31) * 4;
            const int d0 = tid >> 5;      // 0..15
#pragma unroll
            for (int hh = 0; hh < 2; hh++) {
                const int hk = (bx - 10) * 2 + hh;
                unsigned short* dstv = vtb + ((size_t)(bb * NKV + hk) * HD) * SEQ + s_base + half * 128;
#pragma unroll
                for (int i = 0; i < 8; i++) {
                    int d = d0 + 16 * i;
                    ushort4 ov;
                    ov.x = tile[(sc + 0) * 264 + hh * 128 + d];
                    ov.y = tile[(sc + 1) * 264 + hh * 128 + d];
                    ov.z = tile[(sc + 2) * 264 + hh * 128 + d];
                    ov.w = tile[(sc + 3) * 264 + hh * 128 + d];
                    *(ushort4*)(dstv + (size_t)d * SEQ + sc) = ov;
                }
            }
        }
    }
}

// ---------------- GEMM2 v2: 256x128 tile, 8-phase (4 phases x BK=64, dbuf) -----------
// C[M,N] = A[M,K] * W[N,K]^T, bf16 in, f32 out. Grid 16x16 = 256 blocks = 1/CU, full
// machine. 512 threads (2M x 4N waves), per-wave 128x32 via interleaved M-halves.
// LDS 96 KB: A[2buf][256][64] + B[2buf][128][64], chunk-XOR swizzle (kc ^= row&7).
// 6 load-issues/step (A0:2, B:2, A1:2); counted waits: WV4 end-ph1 (A1(t) landed
// before ph2 reads it), WV2 end-ph3 (A0,B of t+1 landed before next ph0 reads).
__global__ __launch_bounds__(512) void gemm_bt(const unsigned short* __restrict__ A,
                                               const unsigned short* __restrict__ W,
                                               float* __restrict__ C, int M, int N, int K) {
    __shared__ unsigned short smem[49152];   // 96 KB
    const int tid  = threadIdx.x;
    const int lane = tid & 63;
    const int wave = tid >> 6;
    const int qm   = lane & 15;
    const int quad = lane >> 4;
    const int wr   = wave >> 2;      // 0..1 (M)
    const int wc   = wave & 3;       // 0..3 (N)
    // XCD swizzle (256 = 8 XCD x 32, bijective)
    const int lin = blockIdx.x + 16 * blockIdx.y;
    const int l2  = (lin & 7) * 32 + (lin >> 3);
    const int m0  = (l2 >> 4) * 256;
    const int n0  = (l2 & 15) * 128;

    f32x4 acc[2][4][2];
#pragma unroll
    for (int a = 0; a < 2; a++)
#pragma unroll
        for (int b = 0; b < 4; b++)
#pragma unroll
            for (int c = 0; c < 2; c++) acc[a][b][c] = (f32x4){0.f, 0.f, 0.f, 0.f};

    const unsigned short* Asrc = A + (size_t)(m0 + (tid >> 3)) * K + (((tid & 7) ^ ((tid >> 3) & 7)) * 8);
    const unsigned short* Bsrc = W + (size_t)(n0 + (tid >> 3)) * K + (((tid & 7) ^ ((tid >> 3) & 7)) * 8);
    const int dstg = tid * 8;
    const int ck0 = ((quad ^ (qm & 7)) * 8);
    const int ck1 = (((4 + quad) ^ (qm & 7)) * 8);
    const int arow = wr * 64 + qm;
    const int brow = wc * 32 + qm;

    short8 af[4][2], bfr[2][2];

#define STG_A2(mh, bufv, kt1) \
    async16(Asrc + (size_t)((mh) * 128) * K + (kt1),      &smem[(bufv) * 16384 + (mh) * 8192 + dstg]); \
    async16(Asrc + (size_t)((mh) * 128 + 64) * K + (kt1), &smem[(bufv) * 16384 + (mh) * 8192 + 4096 + dstg]);
#define STG_Bp(bufv, kt1) \
    async16(Bsrc + (kt1),                  &smem[32768 + (bufv) * 8192 + dstg]); \
    async16(Bsrc + (size_t)64 * K + (kt1), &smem[32768 + (bufv) * 8192 + 4096 + dstg]);

#define RD_A2(p, mh) { \
    _Pragma("unroll") \
    for (int m = 0; m < 4; m++) { \
        af[m][0] = *(const short8*)&smem[(p) * 16384 + ((mh) * 128 + arow + m * 16) * 64 + ck0]; \
        af[m][1] = *(const short8*)&smem[(p) * 16384 + ((mh) * 128 + arow + m * 16) * 64 + ck1]; \
    } }
#define RD_Bp(p) { \
    _Pragma("unroll") \
    for (int n = 0; n < 2; n++) { \
        bfr[n][0] = *(const short8*)&smem[32768 + (p) * 8192 + (brow + n * 16) * 64 + ck0]; \
        bfr[n][1] = *(const short8*)&smem[32768 + (p) * 8192 + (brow + n * 16) * 64 + ck1]; \
    } }
#define MFMA8(mh, kk) { \
    __builtin_amdgcn_s_setprio(1); \
    _Pragma("unroll") \
    for (int m = 0; m < 4; m++) \
        _Pragma("unroll") \
        for (int n = 0; n < 2; n++) \
            acc[mh][m][n] = __builtin_amdgcn_mfma_f32_16x16x32_bf16(af[m][kk], bfr[n][kk], acc[mh][m][n], 0, 0, 0); \
    __builtin_amdgcn_s_setprio(0); }

#define BARb asm volatile("s_barrier" ::: "memory")
#define WB4  asm volatile("s_waitcnt vmcnt(4)" ::: "memory")
#define WB2  asm volatile("s_waitcnt vmcnt(2)" ::: "memory")
#define WB0  asm volatile("s_waitcnt vmcnt(0)" ::: "memory")

    // step t: compute buf p, stage tile t+1 into p^1 (issue order A0, B, A1)
#define STEPB(p, kt1) { \
    /* ph0 mh0/k0 */ RD_A2(p, 0) RD_Bp(p) STG_A2(0, (p)^1, kt1) \
    BARb; MFMA8(0, 0) BARb; \
    /* ph1 mh0/k1 */ STG_Bp((p)^1, kt1) \
    BARb; MFMA8(0, 1) WB4; BARb; \
    /* ph2 mh1/k0 */ RD_A2(p, 1) STG_A2(1, (p)^1, kt1) \
    BARb; MFMA8(1, 0) BARb; \
    /* ph3 mh1/k1 */ MFMA8(1, 1) WB2; BARb; \
}
    // final step: no staging; A1 drained mid-step
#define STEPBE(p) { \
    RD_A2(p, 0) RD_Bp(p) MFMA8(0, 0) MFMA8(0, 1) \
    WB0; BARb; \
    RD_A2(p, 1) MFMA8(1, 0) MFMA8(1, 1) \
}

    // prologue: tile 0 -> buf0 (A0, B, A1 = 6 issues); wait oldest 4 (A0, B)
    STG_A2(0, 0, 0) STG_Bp(0, 0) STG_A2(1, 0, 0)
    WB2; BARb;

#pragma unroll 1
    for (int t2 = 0; t2 < 15; ++t2) {
        STEPB(0, t2 * 128 + 64)
        STEPB(1, t2 * 128 + 128)
    }
    STEPB(0, 1984)    // t=30 stages tile 31
    STEPBE(1)         // t=31
#undef STG_A2
#undef STG_Bp
#undef RD_A2
#undef RD_Bp
#undef MFMA8
#undef STEPB
#undef STEPBE

#pragma unroll
    for (int mh = 0; mh < 2; mh++)
#pragma unroll
        for (int m = 0; m < 4; m++)
#pragma unroll
            for (int r = 0; r < 4; r++) {
                int row = m0 + mh * 128 + wr * 64 + m * 16 + quad * 4 + r;
                float* Crow = C + (size_t)row * N + n0 + wc * 32 + qm;
#pragma unroll
                for (int n = 0; n < 2; n++) Crow[n * 16] = acc[mh][m][n][r];
            }
}

// ---------------- flash attention v5 + T5 setprio: BKV=64, fixed-cap softmax ---------
// LDS exactly 40 KB -> 4 blocks/CU. XOR-swizzled K/V/P chunk layouts, zero pad.
// global_load_lds staging (NOT reg-staging: round-7 showed the allocator spills the
// staging regs to scratch -> 234 MB WRITE_SIZE, 2.5x slower).
__global__ __launch_bounds__(256, 4) void attn(const unsigned short* __restrict__ qb,
                                               const unsigned short* __restrict__ kb,
                                               const unsigned short* __restrict__ vt,
                                               const float* __restrict__ gain,
                                               unsigned short* __restrict__ y) {
    __shared__ unsigned short Ks[8192];      // 64 kv-rows x 128 d, swizzled (16 KB)
    __shared__ unsigned short Vs[8192];      // 128 d-rows x 64 s, swizzled (16 KB)
    __shared__ unsigned short plds[4][1024]; // wave-private P: 16 x 64, swizzled (8 KB)
    const int tid  = threadIdx.x;
    const int lane = tid & 63;
    const int wave = tid >> 6;
    const int bh   = blockIdx.x & 31;
    const int g4   = blockIdx.x >> 5;
    const int gg = g4 & 7;
    const int gs = g4 >> 3;
    const int qt64 = (gs == 0) ? gg : (gs == 1) ? (31 - gg) : (gs == 2) ? (8 + gg) : (23 - gg);
    const int h = bh & 15;
    const int b = bh >> 4;
    const int qm   = lane & 15;
    const int quad = lane >> 4;
    const int q0    = qt64 * 64;
    const int qrow0 = q0 + wave * 16;
    const float M = 17.0f * fabsf(gain[h]);

    const unsigned short* Qp = qb + (((size_t)(b * NH + h)) * SEQ + qrow0) * HD;
    const unsigned short* Kp = kb + ((size_t)(b * NKV + (h >> 2))) * SEQ * HD;
    const unsigned short* Vp = vt + ((size_t)(b * NKV + (h >> 2))) * HD * SEQ;

    short8 qf[4];
#pragma unroll
    for (int c = 0; c < 4; c++)
        qf[c] = *(const short8*)(Qp + qm * HD + c * 32 + quad * 8);

    f32x4 o[8];
#pragma unroll
    for (int t = 0; t < 8; t++) o[t] = (f32x4){0.f, 0.f, 0.f, 0.f};
    float lr[4] = {0.f, 0.f, 0.f, 0.f};

    // K staging: issue i covers rows 16i..16i+15; thread t -> row 16i+(t>>4),
    // global chunk (t&15)^(t>>4) (swizzle by row&15). LDS linear = i*2048 + t*8.
    const unsigned short* KsA = Kp + (size_t)(tid >> 4) * HD + (((tid & 15) ^ (tid >> 4)) & 15) * 8;
    // V staging: issue i covers d-rows 32i..32i+31; thread t -> d 32i+(t>>3),
    // global chunk (t&7)^((t>>3)&7). LDS linear = i*2048 + t*8.
    const unsigned short* VsA = Vp + (size_t)(tid >> 3) * SEQ + (((tid & 7) ^ ((tid >> 3) & 7)) * 8);
    char* KsB = (char*)Ks + wave * 1024;
    char* VsB = (char*)Vs + wave * 1024;
    unsigned short* P = &plds[wave][0];

    const int kvend = q0 + 64;
    for (int kv0 = 0; kv0 < kvend; kv0 += 64) {
#pragma unroll
        for (int i = 0; i < 4; i++) {
            async16(KsA + (size_t)(16 * i) * HD,  KsB + i * 4096);
            async16(VsA + (size_t)(32 * i) * SEQ, VsB + i * 4096);
        }
        KsA += (size_t)64 * HD;
        VsA += 64;
        __syncthreads();

        f32x4 s[4];
#pragma unroll
        for (int g = 0; g < 4; g++) s[g] = (f32x4){0.f, 0.f, 0.f, 0.f};
        __builtin_amdgcn_s_setprio(1);
#pragma unroll
        for (int c = 0; c < 4; c++) {
#pragma unroll
            for (int g = 0; g < 4; g++) {
                short8 kf = *(const short8*)&Ks[(g * 16 + qm) * 128 + (((c * 4 + quad) ^ qm) * 8)];
                s[g] = __builtin_amdgcn_mfma_f32_16x16x32_bf16(qf[c], kf, s[g], 0, 0, 0);
            }
        }
        __builtin_amdgcn_s_setprio(0);
        if (kv0 + 63 > qrow0) {   // final (diagonal) tile only
#pragma unroll
            for (int g = 0; g < 4; g++)
#pragma unroll
                for (int r = 0; r < 4; r++) {
                    int qg = qrow0 + quad * 4 + r;
                    if (kv0 + g * 16 + qm > qg) s[g][r] = -3.0e38f;
                }
        }
        float p[4][4];
#pragma unroll
        for (int g = 0; g < 4; g++)
#pragma unroll
            for (int r = 0; r < 4; r++) {
                p[g][r] = __builtin_amdgcn_exp2f(s[g][r] - M);
                lr[r] += p[g][r];
            }
        // P: C-layout -> A-layout, swizzled chunks (no pad, conflict-free read)
#pragma unroll
        for (int g = 0; g < 4; g++)
#pragma unroll
            for (int r = 0; r < 4; r++) {
                int rowp = quad * 4 + r;
                P[rowp * 64 + (((g * 2 + (qm >> 3)) ^ (rowp & 7)) * 8) + (qm & 7)] = f2bf_pos(p[g][r]);
            }
        short8 pa[2];
#pragma unroll
        for (int ka = 0; ka < 2; ka++)
            pa[ka] = *(const short8*)&P[qm * 64 + (((ka * 4 + quad) ^ (qm & 7)) * 8)];
        __builtin_amdgcn_s_setprio(1);
#pragma unroll
        for (int t = 0; t < 8; t++) {
#pragma unroll
            for (int ka = 0; ka < 2; ka++) {
                short8 vf = *(const short8*)&Vs[(t * 16 + qm) * 64 + (((ka * 4 + quad) ^ (qm & 7)) * 8)];
                o[t] = __builtin_amdgcn_mfma_f32_16x16x32_bf16(pa[ka], vf, o[t], 0, 0, 0);
            }
        }
        __builtin_amdgcn_s_setprio(0);
        __syncthreads();
    }
    float rl[4];
#pragma unroll
    for (int r = 0; r < 4; r++) {
        float l = lr[r];
        l += __shfl_xor(l, 1);
        l += __shfl_xor(l, 2);
        l += __shfl_xor(l, 4);
        l += __shfl_xor(l, 8);
        rl[r] = 1.0f / l;
    }
#pragma unroll
    for (int t = 0; t < 8; t++) {
#pragma unroll
        for (int r = 0; r < 4; r++) {
            size_t row = (size_t)(b * SEQ + qrow0 + quad * 4 + r);
            y[row * D_MODEL + h * HD + t * 16 + qm] = f2bf(o[t][r] * rl[r]);
        }
    }
}

extern "C" void kernel_launch(void* const* d_in, const int* in_sizes, int n_in,
                              void* d_out, int out_size, void* d_ws, size_t ws_size,
                              hipStream_t stream) {
    const float* x  = (const float*)d_in[0];
    const float* Wq = (const float*)d_in[1];
    const float* Wk = (const float*)d_in[2];
    const float* Wv = (const float*)d_in[3];
    const float* Wp = (const float*)d_in[4];
    const float* qg = (const float*)d_in[5];

    char* ws = (char*)d_ws;
    unsigned short* xb   = (unsigned short*)(ws + 0);          // 16 MB (reused as y)
    unsigned short* wqkv = (unsigned short*)(ws + 16777216);   // 12 MB
    unsigned short* wp   = (unsigned short*)(ws + 29360128);   // 8 MB
    unsigned short* qbuf = (unsigned short*)(ws + 37748736);   // 16 MB
    unsigned short* kbuf = (unsigned short*)(ws + 54525952);   // 4 MB
    unsigned short* vtb  = (unsigned short*)(ws + 58720256);   // 4 MB
    unsigned short* y    = xb;                                 // alias: xb dead after GEMM1

    cast_all<<<18432, 256, 0, stream>>>(x, Wq, Wk, Wv, Wp, xb, wqkv, wp);
    gemm_qkv<<<dim3(12, 16), 512, 0, stream>>>(xb, wqkv, qg, qbuf, kbuf, vtb);
    attn<<<1024, 256, 0, stream>>>(qbuf, kbuf, vtb, qg, y);
    gemm_bt<<<dim3(16, 16), 512, 0, stream>>>(y, wp, (float*)d_out, MROWS, D_MODEL, D_MODEL);
}

// Round 10
// 274.919 us; speedup vs baseline: 1.3663x; 1.0005x over previous
//
#include <hip/hip_runtime.h>

#define D_MODEL 2048
#define SEQ 2048
#define BATCH 2
#define NH 16
#define NKV 4
#define HD 128
#define KVD (NKV * HD)              // 512
#define QKVN (D_MODEL + 2 * KVD)    // 3072
#define MROWS (BATCH * SEQ)         // 4096

typedef __attribute__((ext_vector_type(8))) short short8;
typedef __attribute__((ext_vector_type(4))) float f32x4;

__device__ __forceinline__ unsigned short f2bf(float f) {
    union { float f; unsigned int u; } v; v.f = f;
    unsigned int r = (v.u + 0x7FFFu + ((v.u >> 16) & 1u)) >> 16;
    return (unsigned short)r;
}

// round-to-nearest for NON-NEGATIVE floats only (2 ops)
__device__ __forceinline__ unsigned short f2bf_pos(float f) {
    union { float f; unsigned int u; } v; v.f = f;
    return (unsigned short)((v.u + 0x8000u) >> 16);
}

__device__ __forceinline__ float bf2f(unsigned short u) {
    union { float f; unsigned int i; } v; v.i = ((unsigned int)u) << 16;
    return v.f;
}

__device__ __forceinline__ void async16(const void* g, void* l) {
    __builtin_amdgcn_global_load_lds((const __attribute__((address_space(1))) void*)g,
                                     (__attribute__((address_space(3))) void*)l, 16, 0, 0);
}

// ---------------- merged f32 -> bf16 cast for x, Wq, Wk, Wv, Wp (one launch) ----------
__global__ __launch_bounds__(256) void cast_all(const float* __restrict__ x,
                                                const float* __restrict__ wq,
                                                const float* __restrict__ wk,
                                                const float* __restrict__ wv,
                                                const float* __restrict__ wp,
                                                unsigned short* __restrict__ xb,
                                                unsigned short* __restrict__ wqkv,
                                                unsigned short* __restrict__ wpb) {
    int i = blockIdx.x * 256 + threadIdx.x;  // float4 index, regions block-aligned
    const float4* s; ushort4* d; int j;
    if (i < 2097152)      { s = (const float4*)x;  d = (ushort4*)xb;             j = i; }
    else if (i < 3145728) { s = (const float4*)wq; d = (ushort4*)wqkv;           j = i - 2097152; }
    else if (i < 3407872) { s = (const float4*)wk; d = (ushort4*)wqkv + 1048576; j = i - 3145728; }
    else if (i < 3670016) { s = (const float4*)wv; d = (ushort4*)wqkv + 1310720; j = i - 3407872; }
    else                  { s = (const float4*)wp; d = (ushort4*)wpb;            j = i - 3670016; }
    float4 v = s[j];
    ushort4 o;
    o.x = f2bf(v.x); o.y = f2bf(v.y); o.z = f2bf(v.z); o.w = f2bf(v.w);
    d[j] = o;
}

// ---------------- GEMM1 fused, 256x256 8-phase, DEEP prefetch ------------------------
// qkv = x @ Wqkv^T with rmsnorm/rope/gain (q,k) or transpose (v) epilogue.
// 8 waves (2M x 4N), per-wave 128x64 output via interleaved halves.
// LDS 128 KB: A[2buf][256][64] + B[2buf][256][64], chunk-XOR swizzled (kc ^= row&7).
// DEEP pipeline via piece-wise buffer reuse: tile t+2 staged into buf p (the buffer
// being computed) as its regions free — A0+B0 at ph1, B1 at ph2, A1 at ph3. Load
// flight = 5-8 phases (vs 1-4 before). Steady-state waits: vmcnt(10) end-ph0,
// vmcnt(12) end-ph1, none end-ph2, vmcnt(12) end-ph3 (per-wave FIFO-traced).
// XCD-aware bijective swizzle: 192 blocks -> 24 contiguous per XCD.
__global__ __launch_bounds__(512) void gemm_qkv(const unsigned short* __restrict__ A,
                                                const unsigned short* __restrict__ W,
                                                const float* __restrict__ gain,
                                                unsigned short* __restrict__ qbuf,
                                                unsigned short* __restrict__ kbuf,
                                                unsigned short* __restrict__ vtb) {
    __shared__ unsigned short smem[65536];   // 128 KB staging; reused as 128x264 out half-tile
    unsigned short* tile = smem;
    const int K = D_MODEL;
    const int tid  = threadIdx.x;
    const int lane = tid & 63;
    const int wave = tid >> 6;
    const int qm   = lane & 15;
    const int quad = lane >> 4;
    const int wr   = wave >> 2;      // 0..1  (M)
    const int wc   = wave & 3;       // 0..3  (N)
    // XCD swizzle (192 = 8 XCD x 24, bijective)
    const int lin = blockIdx.x + 12 * blockIdx.y;
    const int l2  = (lin & 7) * 24 + (lin >> 3);
    const int bx  = l2 % 12;
    const int m0  = (l2 / 12) * 256;
    const int n0 = bx * 256;

    f32x4 acc[2][2][4][2];
#pragma unroll
    for (int a = 0; a < 2; a++)
#pragma unroll
        for (int b = 0; b < 2; b++)
#pragma unroll
            for (int c = 0; c < 4; c++)
#pragma unroll
                for (int d = 0; d < 2; d++) acc[a][b][c][d] = (f32x4){0.f, 0.f, 0.f, 0.f};

    // staging: thread t -> row t>>3 (of 64-row issue), global chunk (t&7)^((t>>3)&7)
    const unsigned short* Asrc = A + (size_t)(m0 + (tid >> 3)) * K + (((tid & 7) ^ ((tid >> 3) & 7)) * 8);
    const unsigned short* Bsrc = W + (size_t)(n0 + (tid >> 3)) * K + (((tid & 7) ^ ((tid >> 3) & 7)) * 8);
    const int dstg = tid * 8;                       // linear LDS dest (ushort)
    // ds_read chunk offsets (swizzle inverse): logical chunk ks*4+quad, XOR row&7 (= qm&7)
    const int ck0 = ((quad ^ (qm & 7)) * 8);
    const int ck1 = (((4 + quad) ^ (qm & 7)) * 8);
    const int arow = wr * 64 + qm;
    const int brow = wc * 32 + qm;

    short8 af[4][2], bf0[2][2], bf1[2][2];

#define STG_A(mh, bufv, kt1) \
    async16(Asrc + (size_t)((mh) * 128) * K + (kt1),      &smem[(bufv) * 16384 + (mh) * 8192 + dstg]); \
    async16(Asrc + (size_t)((mh) * 128 + 64) * K + (kt1), &smem[(bufv) * 16384 + (mh) * 8192 + 4096 + dstg]);
#define STG_B(nh, bufv, kt1) \
    async16(Bsrc + (size_t)((nh) * 128) * K + (kt1),      &smem[32768 + (bufv) * 16384 + (nh) * 8192 + dstg]); \
    async16(Bsrc + (size_t)((nh) * 128 + 64) * K + (kt1), &smem[32768 + (bufv) * 16384 + (nh) * 8192 + 4096 + dstg]);

#define RD_A(ab, mh) { \
    _Pragma("unroll") \
    for (int m = 0; m < 4; m++) { \
        af[m][0] = *(const short8*)&smem[(ab) + ((mh) * 128 + arow + m * 16) * 64 + ck0]; \
        af[m][1] = *(const short8*)&smem[(ab) + ((mh) * 128 + arow + m * 16) * 64 + ck1]; \
    } }
#define RD_B(bb, nh, dstf) { \
    _Pragma("unroll") \
    for (int n = 0; n < 2; n++) { \
        dstf[n][0] = *(const short8*)&smem[(bb) + ((nh) * 128 + brow + n * 16) * 64 + ck0]; \
        dstf[n][1] = *(const short8*)&smem[(bb) + ((nh) * 128 + brow + n * 16) * 64 + ck1]; \
    } }
#define MFMA16(mh, nh, bfr) { \
    __builtin_amdgcn_s_setprio(1); \
    _Pragma("unroll") \
    for (int m = 0; m < 4; m++) \
        _Pragma("unroll") \
        for (int n = 0; n < 2; n++) { \
            acc[mh][nh][m][n] = __builtin_amdgcn_mfma_f32_16x16x32_bf16(af[m][0], bfr[n][0], acc[mh][nh][m][n], 0, 0, 0); \
            acc[mh][nh][m][n] = __builtin_amdgcn_mfma_f32_16x16x32_bf16(af[m][1], bfr[n][1], acc[mh][nh][m][n], 0, 0, 0); \
        } \
    __builtin_amdgcn_s_setprio(0); }

#define BARv asm volatile("s_barrier" ::: "memory")
#define WV12 asm volatile("s_waitcnt vmcnt(12)" ::: "memory")
#define WV10 asm volatile("s_waitcnt vmcnt(10)" ::: "memory")
#define WV8  asm volatile("s_waitcnt vmcnt(8)" ::: "memory")
#define WV4  asm volatile("s_waitcnt vmcnt(4)" ::: "memory")
#define WV2  asm volatile("s_waitcnt vmcnt(2)" ::: "memory")
#define WV0  asm volatile("s_waitcnt vmcnt(0)" ::: "memory")

    // Step t: compute tile t from buf p (= t%2); stage tile t+2 into buf p as regions
    // free (A0,B0 free after ph0 -> stage at ph1; B1 after ph1 -> ph2; A1 after ph2 -> ph3).
    // Waits traced per-wave (2 loads/piece): see header comment.
#define STEP_D(p, kt2) { \
    /* ph0 (mh0,nh0) */ RD_A((p)*16384, 0) RD_B(32768 + (p)*16384, 0, bf0) \
    BARv; MFMA16(0, 0, bf0) WV10; BARv; \
    /* ph1 (mh0,nh1) */ RD_B(32768 + (p)*16384, 1, bf1) STG_A(0, p, kt2) STG_B(0, p, kt2) \
    BARv; MFMA16(0, 1, bf1) WV12; BARv; \
    /* ph2 (mh1,nh0) */ RD_A((p)*16384, 1) STG_B(1, p, kt2) \
    BARv; MFMA16(1, 0, bf0) BARv; \
    /* ph3 (mh1,nh1) */ STG_A(1, p, kt2) \
    BARv; MFMA16(1, 1, bf1) WV12; BARv; \
}
    // step 30: no staging; drain-adjusted waits (10, 8, -, 4)
#define STEP_D30(p) { \
    RD_A((p)*16384, 0) RD_B(32768 + (p)*16384, 0, bf0) BARv; MFMA16(0, 0, bf0) WV10; BARv; \
    RD_B(32768 + (p)*16384, 1, bf1)                    BARv; MFMA16(0, 1, bf1) WV8;  BARv; \
    RD_A((p)*16384, 1)                                 BARv; MFMA16(1, 0, bf0) BARv; \
    BARv; MFMA16(1, 1, bf1) WV4; BARv; \
}
    // step 31 (last): waits (2, 0, -, -)
#define STEP_D31(p) { \
    RD_A((p)*16384, 0) RD_B(32768 + (p)*16384, 0, bf0) BARv; MFMA16(0, 0, bf0) WV2; BARv; \
    RD_B(32768 + (p)*16384, 1, bf1)                    BARv; MFMA16(0, 1, bf1) WV0; BARv; \
    RD_A((p)*16384, 1)                                 BARv; MFMA16(1, 0, bf0) BARv; \
    MFMA16(1, 1, bf1) \
}

    // prologue: tiles 0 and 1 fully staged (16 loads/wave); need A0,B0(0) -> vmcnt(12)
    STG_A(0, 0, 0)  STG_B(0, 0, 0)  STG_B(1, 0, 0)  STG_A(1, 0, 0)
    STG_A(0, 1, 64) STG_B(0, 1, 64) STG_B(1, 1, 64) STG_A(1, 1, 64)
    WV12; BARv;

#pragma unroll 1
    for (int t2 = 0; t2 < 15; ++t2) {
        STEP_D(0, t2 * 128 + 128)    // step 2i   stages tile 2i+2
        STEP_D(1, t2 * 128 + 192)    // step 2i+1 stages tile 2i+3
    }
    STEP_D30(0)   // step 30 (tile 30)
    STEP_D31(1)   // step 31 (tile 31)
#undef STG_A
#undef STG_B
#undef RD_A
#undef RD_B
#undef MFMA16
#undef STEP_D
#undef STEP_D30
#undef STEP_D31

    // ---- fused epilogue, two 128-row halves (out half-tile 128 x 264 in reused LDS) --
    const int s_base = m0 & 2047;   // 256-aligned, batch doesn't split a tile
    const int bb = m0 >> 11;
    const float invf = __builtin_amdgcn_exp2f(-(float)lane * 0.20761871f - 2.6514961f);

#pragma unroll
    for (int half = 0; half < 2; ++half) {
        __syncthreads();   // prior reads (K-loop ds_reads or half-0 processing) done
#pragma unroll
        for (int nh = 0; nh < 2; nh++)
#pragma unroll
            for (int m = 0; m < 4; m++)
#pragma unroll
                for (int n = 0; n < 2; n++)
#pragma unroll
                    for (int r = 0; r < 4; r++) {
                        int row = wr * 64 + m * 16 + quad * 4 + r;
                        int col = nh * 128 + wc * 32 + n * 16 + qm;
                        tile[row * 264 + col] = f2bf(acc[half][nh][m][n][r]);
                    }
        __syncthreads();

        if (bx < 10) {
            // q heads (bx<8): h = 2bx+hh; k heads (bx 8,9): hk = (bx-8)*2+hh
            const bool isq = bx < 8;
#pragma unroll
            for (int hh = 0; hh < 2; hh++) {
                const int h = (isq ? 2 * bx : (bx - 8) * 2) + hh;
                const float g = isq ? gain[h] * 0.12751744f : 1.0f;  // (1/sqrt(128))*log2e folded
                unsigned short* dst = isq
                    ? qbuf + ((size_t)(bb * NH + h) * SEQ + s_base + half * 128) * HD
                    : kbuf + ((size_t)(bb * NKV + h) * SEQ + s_base + half * 128) * HD;
                for (int rr = 0; rr < 16; rr++) {
                    int row = wave * 16 + rr;
                    float x1 = bf2f(tile[row * 264 + hh * 128 + lane]);
                    float x2 = bf2f(tile[row * 264 + hh * 128 + 64 + lane]);
                    float ss = x1 * x1 + x2 * x2;
                    ss += __shfl_xor(ss, 1);  ss += __shfl_xor(ss, 2);  ss += __shfl_xor(ss, 4);
                    ss += __shfl_xor(ss, 8);  ss += __shfl_xor(ss, 16); ss += __shfl_xor(ss, 32);
                    float rs = rsqrtf(ss * (1.0f / 128.0f) + 1.1920929e-07f);
                    float rev = (float)(s_base + half * 128 + row) * invf;  // revolutions, >= 0
                    rev -= truncf(rev);
                    float sn = __builtin_amdgcn_sinf(rev);
                    float cs = __builtin_amdgcn_cosf(rev);
                    float a1 = x1 * rs, a2 = x2 * rs;
                    float o1 = (a1 * cs + a2 * sn) * g;
                    float o2 = (a2 * cs - a1 * sn) * g;
                    dst[(size_t)row * HD + lane]      = f2bf(o1);
                    dst[(size_t)row * HD + 64 + lane] = f2bf(o2);
                }
            }
        } else {
            // v heads: write transposed vt[b][hk][d][s]; hk = (bx-10)*2 + hh
            const int sc = (tid & 31) * 4;
            const int d0 = tid >> 5;      // 0..15
#pragma unroll
            for (int hh = 0; hh < 2; hh++) {
                const int hk = (bx - 10) * 2 + hh;
                unsigned short* dstv = vtb + ((size_t)(bb * NKV + hk) * HD) * SEQ + s_base + half * 128;
#pragma unroll
                for (int i = 0; i < 8; i++) {
                    int d = d0 + 16 * i;
                    ushort4 ov;
                    ov.x = tile[(sc + 0) * 264 + hh * 128 + d];
                    ov.y = tile[(sc + 1) * 264 + hh * 128 + d];
                    ov.z = tile[(sc + 2) * 264 + hh * 128 + d];
                    ov.w = tile[(sc + 3) * 264 + hh * 128 + d];
                    *(ushort4*)(dstv + (size_t)d * SEQ + sc) = ov;
                }
            }
        }
    }
}

// ---------------- GEMM2 v2: 256x128 tile, 8-phase (4 phases x BK=64, dbuf) -----------
// C[M,N] = A[M,K] * W[N,K]^T, bf16 in, f32 out. Grid 16x16 = 256 blocks = 1/CU, full
// machine. 512 threads (2M x 4N waves), per-wave 128x32 via interleaved M-halves.
// LDS 96 KB: A[2buf][256][64] + B[2buf][128][64], chunk-XOR swizzle (kc ^= row&7).
// 6 load-issues/step (A0:2, B:2, A1:2); counted waits: WV4 end-ph1 (A1(t) landed
// before ph2 reads it), WV2 end-ph3 (A0,B of t+1 landed before next ph0 reads).
__global__ __launch_bounds__(512) void gemm_bt(const unsigned short* __restrict__ A,
                                               const unsigned short* __restrict__ W,
                                               float* __restrict__ C, int M, int N, int K) {
    __shared__ unsigned short smem[49152];   // 96 KB
    const int tid  = threadIdx.x;
    const int lane = tid & 63;
    const int wave = tid >> 6;
    const int qm   = lane & 15;
    const int quad = lane >> 4;
    const int wr   = wave >> 2;      // 0..1 (M)
    const int wc   = wave & 3;       // 0..3 (N)
    // XCD swizzle (256 = 8 XCD x 32, bijective)
    const int lin = blockIdx.x + 16 * blockIdx.y;
    const int l2  = (lin & 7) * 32 + (lin >> 3);
    const int m0  = (l2 >> 4) * 256;
    const int n0  = (l2 & 15) * 128;

    f32x4 acc[2][4][2];
#pragma unroll
    for (int a = 0; a < 2; a++)
#pragma unroll
        for (int b = 0; b < 4; b++)
#pragma unroll
            for (int c = 0; c < 2; c++) acc[a][b][c] = (f32x4){0.f, 0.f, 0.f, 0.f};

    const unsigned short* Asrc = A + (size_t)(m0 + (tid >> 3)) * K + (((tid & 7) ^ ((tid >> 3) & 7)) * 8);
    const unsigned short* Bsrc = W + (size_t)(n0 + (tid >> 3)) * K + (((tid & 7) ^ ((tid >> 3) & 7)) * 8);
    const int dstg = tid * 8;
    const int ck0 = ((quad ^ (qm & 7)) * 8);
    const int ck1 = (((4 + quad) ^ (qm & 7)) * 8);
    const int arow = wr * 64 + qm;
    const int brow = wc * 32 + qm;

    short8 af[4][2], bfr[2][2];

#define STG_A2(mh, bufv, kt1) \
    async16(Asrc + (size_t)((mh) * 128) * K + (kt1),      &smem[(bufv) * 16384 + (mh) * 8192 + dstg]); \
    async16(Asrc + (size_t)((mh) * 128 + 64) * K + (kt1), &smem[(bufv) * 16384 + (mh) * 8192 + 4096 + dstg]);
#define STG_Bp(bufv, kt1) \
    async16(Bsrc + (kt1),                  &smem[32768 + (bufv) * 8192 + dstg]); \
    async16(Bsrc + (size_t)64 * K + (kt1), &smem[32768 + (bufv) * 8192 + 4096 + dstg]);

#define RD_A2(p, mh) { \
    _Pragma("unroll") \
    for (int m = 0; m < 4; m++) { \
        af[m][0] = *(const short8*)&smem[(p) * 16384 + ((mh) * 128 + arow + m * 16) * 64 + ck0]; \
        af[m][1] = *(const short8*)&smem[(p) * 16384 + ((mh) * 128 + arow + m * 16) * 64 + ck1]; \
    } }
#define RD_Bp(p) { \
    _Pragma("unroll") \
    for (int n = 0; n < 2; n++) { \
        bfr[n][0] = *(const short8*)&smem[32768 + (p) * 8192 + (brow + n * 16) * 64 + ck0]; \
        bfr[n][1] = *(const short8*)&smem[32768 + (p) * 8192 + (brow + n * 16) * 64 + ck1]; \
    } }
#define MFMA8(mh, kk) { \
    __builtin_amdgcn_s_setprio(1); \
    _Pragma("unroll") \
    for (int m = 0; m < 4; m++) \
        _Pragma("unroll") \
        for (int n = 0; n < 2; n++) \
            acc[mh][m][n] = __builtin_amdgcn_mfma_f32_16x16x32_bf16(af[m][kk], bfr[n][kk], acc[mh][m][n], 0, 0, 0); \
    __builtin_amdgcn_s_setprio(0); }

#define BARb asm volatile("s_barrier" ::: "memory")
#define WB4  asm volatile("s_waitcnt vmcnt(4)" ::: "memory")
#define WB2  asm volatile("s_waitcnt vmcnt(2)" ::: "memory")
#define WB0  asm volatile("s_waitcnt vmcnt(0)" ::: "memory")

    // step t: compute buf p, stage tile t+1 into p^1 (issue order A0, B, A1)
#define STEPB(p, kt1) { \
    /* ph0 mh0/k0 */ RD_A2(p, 0) RD_Bp(p) STG_A2(0, (p)^1, kt1) \
    BARb; MFMA8(0, 0) BARb; \
    /* ph1 mh0/k1 */ STG_Bp((p)^1, kt1) \
    BARb; MFMA8(0, 1) WB4; BARb; \
    /* ph2 mh1/k0 */ RD_A2(p, 1) STG_A2(1, (p)^1, kt1) \
    BARb; MFMA8(1, 0) BARb; \
    /* ph3 mh1/k1 */ MFMA8(1, 1) WB2; BARb; \
}
    // final step: no staging; A1 drained mid-step
#define STEPBE(p) { \
    RD_A2(p, 0) RD_Bp(p) MFMA8(0, 0) MFMA8(0, 1) \
    WB0; BARb; \
    RD_A2(p, 1) MFMA8(1, 0) MFMA8(1, 1) \
}

    // prologue: tile 0 -> buf0 (A0, B, A1 = 6 issues); wait oldest 4 (A0, B)
    STG_A2(0, 0, 0) STG_Bp(0, 0) STG_A2(1, 0, 0)
    WB2; BARb;

#pragma unroll 1
    for (int t2 = 0; t2 < 15; ++t2) {
        STEPB(0, t2 * 128 + 64)
        STEPB(1, t2 * 128 + 128)
    }
    STEPB(0, 1984)    // t=30 stages tile 31
    STEPBE(1)         // t=31
#undef STG_A2
#undef STG_Bp
#undef RD_A2
#undef RD_Bp
#undef MFMA8
#undef STEPB
#undef STEPBE

#pragma unroll
    for (int mh = 0; mh < 2; mh++)
#pragma unroll
        for (int m = 0; m < 4; m++)
#pragma unroll
            for (int r = 0; r < 4; r++) {
                int row = m0 + mh * 128 + wr * 64 + m * 16 + quad * 4 + r;
                float* Crow = C + (size_t)row * N + n0 + wc * 32 + qm;
#pragma unroll
                for (int n = 0; n < 2; n++) Crow[n * 16] = acc[mh][m][n][r];
            }
}

// ---------------- flash attention v5 + T5 setprio: BKV=64, fixed-cap softmax ---------
// LDS exactly 40 KB -> 4 blocks/CU. XOR-swizzled K/V/P chunk layouts, zero pad.
// global_load_lds staging (NOT reg-staging: round-7 showed the allocator spills the
// staging regs to scratch -> 234 MB WRITE_SIZE, 2.5x slower).
__global__ __launch_bounds__(256, 4) void attn(const unsigned short* __restrict__ qb,
                                               const unsigned short* __restrict__ kb,
                                               const unsigned short* __restrict__ vt,
                                               const float* __restrict__ gain,
                                               unsigned short* __restrict__ y) {
    __shared__ unsigned short Ks[8192];      // 64 kv-rows x 128 d, swizzled (16 KB)
    __shared__ unsigned short Vs[8192];      // 128 d-rows x 64 s, swizzled (16 KB)
    __shared__ unsigned short plds[4][1024]; // wave-private P: 16 x 64, swizzled (8 KB)
    const int tid  = threadIdx.x;
    const int lane = tid & 63;
    const int wave = tid >> 6;
    const int bh   = blockIdx.x & 31;
    const int g4   = blockIdx.x >> 5;
    const int gg = g4 & 7;
    const int gs = g4 >> 3;
    const int qt64 = (gs == 0) ? gg : (gs == 1) ? (31 - gg) : (gs == 2) ? (8 + gg) : (23 - gg);
    const int h = bh & 15;
    const int b = bh >> 4;
    const int qm   = lane & 15;
    const int quad = lane >> 4;
    const int q0    = qt64 * 64;
    const int qrow0 = q0 + wave * 16;
    const float M = 17.0f * fabsf(gain[h]);

    const unsigned short* Qp = qb + (((size_t)(b * NH + h)) * SEQ + qrow0) * HD;
    const unsigned short* Kp = kb + ((size_t)(b * NKV + (h >> 2))) * SEQ * HD;
    const unsigned short* Vp = vt + ((size_t)(b * NKV + (h >> 2))) * HD * SEQ;

    short8 qf[4];
#pragma unroll
    for (int c = 0; c < 4; c++)
        qf[c] = *(const short8*)(Qp + qm * HD + c * 32 + quad * 8);

    f32x4 o[8];
#pragma unroll
    for (int t = 0; t < 8; t++) o[t] = (f32x4){0.f, 0.f, 0.f, 0.f};
    float lr[4] = {0.f, 0.f, 0.f, 0.f};

    // K staging: issue i covers rows 16i..16i+15; thread t -> row 16i+(t>>4),
    // global chunk (t&15)^(t>>4) (swizzle by row&15). LDS linear = i*2048 + t*8.
    const unsigned short* KsA = Kp + (size_t)(tid >> 4) * HD + (((tid & 15) ^ (tid >> 4)) & 15) * 8;
    // V staging: issue i covers d-rows 32i..32i+31; thread t -> d 32i+(t>>3),
    // global chunk (t&7)^((t>>3)&7). LDS linear = i*2048 + t*8.
    const unsigned short* VsA = Vp + (size_t)(tid >> 3) * SEQ + (((tid & 7) ^ ((tid >> 3) & 7)) * 8);
    char* KsB = (char*)Ks + wave * 1024;
    char* VsB = (char*)Vs + wave * 1024;
    unsigned short* P = &plds[wave][0];

    const int kvend = q0 + 64;
    for (int kv0 = 0; kv0 < kvend; kv0 += 64) {
#pragma unroll
        for (int i = 0; i < 4; i++) {
            async16(KsA + (size_t)(16 * i) * HD,  KsB + i * 4096);
            async16(VsA + (size_t)(32 * i) * SEQ, VsB + i * 4096);
        }
        KsA += (size_t)64 * HD;
        VsA += 64;
        __syncthreads();

        f32x4 s[4];
#pragma unroll
        for (int g = 0; g < 4; g++) s[g] = (f32x4){0.f, 0.f, 0.f, 0.f};
        __builtin_amdgcn_s_setprio(1);
#pragma unroll
        for (int c = 0; c < 4; c++) {
#pragma unroll
            for (int g = 0; g < 4; g++) {
                short8 kf = *(const short8*)&Ks[(g * 16 + qm) * 128 + (((c * 4 + quad) ^ qm) * 8)];
                s[g] = __builtin_amdgcn_mfma_f32_16x16x32_bf16(qf[c], kf, s[g], 0, 0, 0);
            }
        }
        __builtin_amdgcn_s_setprio(0);
        if (kv0 + 63 > qrow0) {   // final (diagonal) tile only
#pragma unroll
            for (int g = 0; g < 4; g++)
#pragma unroll
                for (int r = 0; r < 4; r++) {
                    int qg = qrow0 + quad * 4 + r;
                    if (kv0 + g * 16 + qm > qg) s[g][r] = -3.0e38f;
                }
        }
        float p[4][4];
#pragma unroll
        for (int g = 0; g < 4; g++)
#pragma unroll
            for (int r = 0; r < 4; r++) {
                p[g][r] = __builtin_amdgcn_exp2f(s[g][r] - M);
                lr[r] += p[g][r];
            }
        // P: C-layout -> A-layout, swizzled chunks (no pad, conflict-free read)
#pragma unroll
        for (int g = 0; g < 4; g++)
#pragma unroll
            for (int r = 0; r < 4; r++) {
                int rowp = quad * 4 + r;
                P[rowp * 64 + (((g * 2 + (qm >> 3)) ^ (rowp & 7)) * 8) + (qm & 7)] = f2bf_pos(p[g][r]);
            }
        short8 pa[2];
#pragma unroll
        for (int ka = 0; ka < 2; ka++)
            pa[ka] = *(const short8*)&P[qm * 64 + (((ka * 4 + quad) ^ (qm & 7)) * 8)];
        __builtin_amdgcn_s_setprio(1);
#pragma unroll
        for (int t = 0; t < 8; t++) {
#pragma unroll
            for (int ka = 0; ka < 2; ka++) {
                short8 vf = *(const short8*)&Vs[(t * 16 + qm) * 64 + (((ka * 4 + quad) ^ (qm & 7)) * 8)];
                o[t] = __builtin_amdgcn_mfma_f32_16x16x32_bf16(pa[ka], vf, o[t], 0, 0, 0);
            }
        }
        __builtin_amdgcn_s_setprio(0);
        __syncthreads();
    }
    float rl[4];
#pragma unroll
    for (int r = 0; r < 4; r++) {
        float l = lr[r];
        l += __shfl_xor(l, 1);
        l += __shfl_xor(l, 2);
        l += __shfl_xor(l, 4);
        l += __shfl_xor(l, 8);
        rl[r] = 1.0f / l;
    }
#pragma unroll
    for (int t = 0; t < 8; t++) {
#pragma unroll
        for (int r = 0; r < 4; r++) {
            size_t row = (size_t)(b * SEQ + qrow0 + quad * 4 + r);
            y[row * D_MODEL + h * HD + t * 16 + qm] = f2bf(o[t][r] * rl[r]);
        }
    }
}

extern "C" void kernel_launch(void* const* d_in, const int* in_sizes, int n_in,
                              void* d_out, int out_size, void* d_ws, size_t ws_size,
                              hipStream_t stream) {
    const float* x  = (const float*)d_in[0];
    const float* Wq = (const float*)d_in[1];
    const float* Wk = (const float*)d_in[2];
    const float* Wv = (const float*)d_in[3];
    const float* Wp = (const float*)d_in[4];
    const float* qg = (const float*)d_in[5];

    char* ws = (char*)d_ws;
    unsigned short* xb   = (unsigned short*)(ws + 0);          // 16 MB (reused as y)
    unsigned short* wqkv = (unsigned short*)(ws + 16777216);   // 12 MB
    unsigned short* wp   = (unsigned short*)(ws + 29360128);   // 8 MB
    unsigned short* qbuf = (unsigned short*)(ws + 37748736);   // 16 MB
    unsigned short* kbuf = (unsigned short*)(ws + 54525952);   // 4 MB
    unsigned short* vtb  = (unsigned short*)(ws + 58720256);   // 4 MB
    unsigned short* y    = xb;                                 // alias: xb dead after GEMM1

    cast_all<<<18432, 256, 0, stream>>>(x, Wq, Wk, Wv, Wp, xb, wqkv, wp);
    gemm_qkv<<<dim3(12, 16), 512, 0, stream>>>(xb, wqkv, qg, qbuf, kbuf, vtb);
    attn<<<1024, 256, 0, stream>>>(qbuf, kbuf, vtb, qg, y);
    gemm_bt<<<dim3(16, 16), 512, 0, stream>>>(y, wp, (float*)d_out, MROWS, D_MODEL, D_MODEL);
}